// Round 14
// baseline (789.995 us; speedup 1.0000x reference)
//
#include <hip/hip_runtime.h>
#include <hip/hip_bf16.h>

#define NN 50000   // nodes
#define NP 50048   // padded rows for Q/K/V/S (unguarded GEMM stores)
#define NE 400000  // edges
#define DD 384     // input dim
#define HC 512     // heads * per-head dim (4 heads x 128)

typedef unsigned int u32;
typedef unsigned short u16;
typedef __attribute__((ext_vector_type(8))) short bf16x8;  // 8 bf16 (4 VGPRs)
typedef __attribute__((ext_vector_type(4))) float f32x4;

#define AS1 __attribute__((address_space(1)))
#define AS3 __attribute__((address_space(3)))

__device__ __forceinline__ float bflo(u32 u){ return __uint_as_float(u << 16); }
__device__ __forceinline__ float bfhi(u32 u){ return __uint_as_float(u & 0xFFFF0000u); }
__device__ __forceinline__ u16 f2bf(float f){
    u32 u = __float_as_uint(f);
    return (u16)((u + 0x7FFFu + ((u >> 16) & 1u)) >> 16);   // RNE
}
__device__ __forceinline__ u32 pack2(float a, float b){
    return (u32)f2bf(a) | ((u32)f2bf(b) << 16);
}
__device__ __forceinline__ float dot8(const float* q, uint4 k){
    return q[0] * bflo(k.x) + q[1] * bfhi(k.x)
         + q[2] * bflo(k.y) + q[3] * bfhi(k.y)
         + q[4] * bflo(k.z) + q[5] * bfhi(k.z)
         + q[6] * bflo(k.w) + q[7] * bfhi(k.w);
}

// ---------------------------------------------------------------------------
// Persistent weight-stationary QKVS GEMM — r8 engine (best measured: 176us)
// with the store-drain defect fixed:
//  * outputs padded to NP rows -> UNGUARDED stores, uniform 32/thread
//  * stageA(t+2) issued BEFORE the epilogue stores
//  * first two steps after a panel epilogue wait vmcnt(34) = exactly the
//    {2 next-stage loads + 32 stores} younger than the awaited stage
//    (vmcnt retires in order, so 34 is exact, not heuristic)
// ---------------------------------------------------------------------------
template<int K>
__global__ __launch_bounds__(512)
void gemm_ws(const u16* __restrict__ Ab, const u16* __restrict__ Wb,
             const float* __restrict__ bias,
             u16* __restrict__ oQ, u16* __restrict__ oK,
             u16* __restrict__ oV, u16* __restrict__ oS)
{
    constexpr int NKT  = K / 64;        // A k-chunks per panel
    constexpr int WCH  = K / 8;         // 16B chunks per W row
    constexpr int NPAN = (NN + 127) / 128;
    __shared__ char smW[128 * K * 2];   // 128 KB @K=512, 96 KB @K=384
    __shared__ char smA[2][16384];      // [buf][128 rows][64 k x 2B]

    const int b   = blockIdx.x;
    const int xcd = b & 7;
    const int idx = b >> 3;
    const int ct  = idx & 15;           // col-tile (128 cols of 2048)
    const int rh  = idx >> 4;           // row-half (0/1)

    const int tid  = threadIdx.x;
    const int lane = tid & 63;
    const int w    = tid >> 6;
    const int wq   = w >> 1;            // row quarter 0..3 (32 rows)
    const int wc   = w & 1;             // col half 0..1 (64 cols)
    const int r16  = lane & 15;
    const int kq   = lane >> 4;

    // ---- stage W once ----
    const u16* Wrow0 = Wb + (size_t)ct * 128 * K;
    #pragma unroll
    for (int p = 0; p < (128 * WCH) / 512; ++p) {
        int ci = p * 512 + tid;
        int row = ci / WCH, pc = ci % WCH;
        int lc = (pc & ~7) | ((pc ^ row) & 7);
        __builtin_amdgcn_global_load_lds((const AS1 u32*)(Wrow0 + (size_t)row * K + lc * 8),
                                         (AS3 u32*)(smW + (size_t)ci * 16), 16, 0, 0);
    }

    // ---- panel list: p = (2j+rh)*8 + xcd ----
    auto panel = [&](int j) { return (2 * j + rh) * 8 + xcd; };
    int np = 0;
    while (panel(np) < NPAN) ++np;      // 24 or 25
    const int total = np * NKT;

    // A stage: 1024 chunks over 512 threads -> 2 gload_lds/thread
    auto stageA = [&](int t) {
        int j = t / NKT, kc = t - (t / NKT) * NKT;
        int m0 = panel(j) * 128;
        #pragma unroll
        for (int p = 0; p < 2; ++p) {
            int ci = p * 512 + tid;
            int row = ci >> 3, pc = ci & 7;
            int lc = pc ^ (row & 7);
            int gr = m0 + row; if (gr >= NN) gr = NN - 1;
            __builtin_amdgcn_global_load_lds((const AS1 u32*)(Ab + (size_t)gr * K + kc * 64 + lc * 8),
                                             (AS3 u32*)(smA[t & 1] + ci * 16), 16, 0, 0);
        }
    };

    stageA(0);
    stageA(1);

    f32x4 acc[2][4] = {};

    const int qsel = ct >> 2;
    u16* outp = (qsel == 0) ? oQ : (qsel == 1) ? oK : (qsel == 2) ? oV : oS;
    const int cb = (ct & 3) * 128 + wc * 64;
    float bv4[4];
    #pragma unroll
    for (int ni = 0; ni < 4; ++ni) bv4[ni] = bias[ct * 128 + wc * 64 + ni * 16 + r16];

    for (int t = 0; t < total; ++t) {
        const int jj = t / NKT;
        const int kt = t - jj * NKT;
        if (t + 1 >= total)          { asm volatile("s_waitcnt vmcnt(0)"  ::: "memory"); }
        else if (t > 1 && kt <= 1)   { asm volatile("s_waitcnt vmcnt(34)" ::: "memory"); }
        else                         { asm volatile("s_waitcnt vmcnt(2)"  ::: "memory"); }
        __builtin_amdgcn_s_barrier();          // stage(t) landed for all waves
        __builtin_amdgcn_sched_barrier(0);

        const char* bufA = smA[t & 1];
        #pragma unroll
        for (int kk = 0; kk < 2; ++kk) {
            bf16x8 av[2], bv[4];
            #pragma unroll
            for (int i = 0; i < 2; ++i) {
                int rowA = wq * 32 + i * 16 + r16;
                int c = kk * 4 + kq;
                av[i] = *(const bf16x8*)(bufA + rowA * 128 + ((c ^ (rowA & 7)) << 4));
            }
            #pragma unroll
            for (int i = 0; i < 4; ++i) {
                int rowW = wc * 64 + i * 16 + r16;
                int c = kt * 8 + kk * 4 + kq;
                int pcw = (c & ~7) | ((c ^ rowW) & 7);
                bv[i] = *(const bf16x8*)(smW + (size_t)rowW * (K * 2) + (pcw << 4));
            }
            #pragma unroll
            for (int mi = 0; mi < 2; ++mi)
                #pragma unroll
                for (int ni = 0; ni < 4; ++ni)
                    acc[mi][ni] = __builtin_amdgcn_mfma_f32_16x16x32_bf16(
                        av[mi], bv[ni], acc[mi][ni], 0, 0, 0);
        }

        __builtin_amdgcn_sched_barrier(0);
        __builtin_amdgcn_s_barrier();          // all waves done reading buf t&1
        __builtin_amdgcn_sched_barrier(0);

        if (t + 2 < total) stageA(t + 2);      // issue BEFORE epilogue stores

        if (kt == NKT - 1) {                   // panel finished: epilogue
            int m0 = panel(jj) * 128;          // rows < NP always (padded out)
            #pragma unroll
            for (int ni = 0; ni < 4; ++ni) {
                int col = cb + ni * 16 + r16;
                float bb = bv4[ni];
                #pragma unroll
                for (int mi = 0; mi < 2; ++mi)
                    #pragma unroll
                    for (int r = 0; r < 4; ++r) {
                        int gr = m0 + wq * 32 + mi * 16 + kq * 4 + r;
                        outp[(size_t)gr * 512 + col] = f2bf(acc[mi][ni][r] + bb);
                        acc[mi][ni][r] = 0.f;
                    }
            }
        }
    }
}

// ---------------------------------------------------------------------------
// 2-deep pipelined MFMA GEMM — output projection (r7-proven form).
// ---------------------------------------------------------------------------
template<int K>
__global__ __launch_bounds__(256)
void gemm2ph(const u16* __restrict__ Ab, const u16* __restrict__ Wb,
             const float* __restrict__ bias, float* __restrict__ oF,
             int n, int Ototal, int NT)
{
    constexpr int NKT = K / 64;
    __shared__ char smA[2][16384];
    __shared__ char smB[2][16384];

    const int nb  = gridDim.x;
    const int bd  = blockIdx.x;
    const int q8  = nb >> 3, r8 = nb & 7;
    const int xcd = bd & 7, gg = bd >> 3;
    const int tt  = (xcd < r8 ? xcd * (q8 + 1) : r8 * (q8 + 1) + (xcd - r8) * q8) + gg;
    const int m0  = (tt / NT) * 128;
    const int o0  = (tt % NT) * 128;

    const int tid  = threadIdx.x;
    const int lane = tid & 63;
    const int w    = tid >> 6;
    const int wr   = w >> 1, wc = w & 1;
    const int r16  = lane & 15;
    const int kq   = lane >> 4;
    const int swz  = (r16 & 7) << 4;

    auto stage = [&](int bf, int kt) {
        #pragma unroll
        for (int p = 0; p < 4; ++p) {
            int ci = p * 256 + tid, row = ci >> 3, pc = ci & 7;
            int lc = pc ^ (row & 7);
            const u16* g = Wb + (size_t)(o0 + row) * K + kt * 64 + lc * 8;
            __builtin_amdgcn_global_load_lds((const AS1 u32*)g,
                                             (AS3 u32*)(smB[bf] + ci * 16), 16, 0, 0);
        }
        #pragma unroll
        for (int p = 0; p < 4; ++p) {
            int ci = p * 256 + tid, row = ci >> 3, pc = ci & 7;
            int lc = pc ^ (row & 7);
            int gr = m0 + row; if (gr >= n) gr = n - 1;
            const u16* g = Ab + (size_t)gr * K + kt * 64 + lc * 8;
            __builtin_amdgcn_global_load_lds((const AS1 u32*)g,
                                             (AS3 u32*)(smA[bf] + ci * 16), 16, 0, 0);
        }
    };

    f32x4 acc[4][4] = {};

    stage(0, 0);
    stage(1, 1);

    for (int kt = 0; kt < NKT; ++kt) {
        if (kt + 1 < NKT) { asm volatile("s_waitcnt vmcnt(8)" ::: "memory"); }
        else             { asm volatile("s_waitcnt vmcnt(0)" ::: "memory"); }
        __builtin_amdgcn_s_barrier();
        __builtin_amdgcn_sched_barrier(0);

        const char* pa = smA[kt & 1] + (wr * 64) * 128;
        const char* pb = smB[kt & 1] + (wc * 64) * 128;
        #pragma unroll
        for (int kk = 0; kk < 2; ++kk) {
            const int kb = kk * 64 + kq * 16;
            bf16x8 av[4], bv[4];
            #pragma unroll
            for (int i = 0; i < 4; ++i) {
                av[i] = *(const bf16x8*)(pa + (i * 16 + r16) * 128 + (kb ^ swz));
                bv[i] = *(const bf16x8*)(pb + (i * 16 + r16) * 128 + (kb ^ swz));
            }
            #pragma unroll
            for (int mi = 0; mi < 4; ++mi)
                #pragma unroll
                for (int ni = 0; ni < 4; ++ni)
                    acc[mi][ni] = __builtin_amdgcn_mfma_f32_16x16x32_bf16(
                        av[mi], bv[ni], acc[mi][ni], 0, 0, 0);
        }

        __builtin_amdgcn_sched_barrier(0);
        __builtin_amdgcn_s_barrier();
        __builtin_amdgcn_sched_barrier(0);
        if (kt + 2 < NKT) stage(kt & 1, kt + 2);
    }

    const int cbo = o0 + wc * 64;
    #pragma unroll
    for (int ni = 0; ni < 4; ++ni) {
        int col = cbo + ni * 16 + r16;
        float bb = bias[col];
        #pragma unroll
        for (int mi = 0; mi < 4; ++mi)
            #pragma unroll
            for (int r = 0; r < 4; ++r) {
                int gr = m0 + wr * 64 + mi * 16 + kq * 4 + r;
                if (gr < n) oF[(size_t)gr * Ototal + col] = acc[mi][ni][r] + bb;
            }
    }
}

// ---------------------------------------------------------------------------
// Fused fp32 -> bf16 conversion of x + all 9 weight matrices (one launch).
#define XG  2400000      // 50000*384/8
#define W0G 24576        // 512*384/8 per matrix
#define W1G 32768        // 512*512/8 per matrix
#define WOG 24576        // 384*512/8
#define CVT_TOTAL (XG + 4*W0G + 4*W1G + WOG)

__global__ __launch_bounds__(256)
void cvt_all(const float* __restrict__ x,
             const float* q0w, const float* k0w, const float* v0w, const float* s0w,
             const float* q1w, const float* k1w, const float* v1w, const float* s1w,
             const float* ow,
             u16* __restrict__ Xb, u16* __restrict__ Wc0,
             u16* __restrict__ Wc1, u16* __restrict__ WcO)
{
    int i = blockIdx.x * 256 + threadIdx.x;
    if (i >= CVT_TOTAL) return;
    const float* s; u16* d; int g;
    if (i < XG) { s = x; d = Xb; g = i; }
    else {
        int j = i - XG;
        if (j < 4 * W0G) {
            int q = j / W0G; g = j - q * W0G;
            s = (q == 0 ? q0w : q == 1 ? k0w : q == 2 ? v0w : s0w);
            d = Wc0 + (size_t)q * W0G * 8;
        } else if ((j -= 4 * W0G) < 4 * W1G) {
            int q = j / W1G; g = j - q * W1G;
            s = (q == 0 ? q1w : q == 1 ? k1w : q == 2 ? v1w : s1w);
            d = Wc1 + (size_t)q * W1G * 8;
        } else { j -= 4 * W1G; s = ow; d = WcO; g = j; }
    }
    float4 f0 = ((const float4*)s)[(size_t)g * 2];
    float4 f1 = ((const float4*)s)[(size_t)g * 2 + 1];
    uint4 o;
    o.x = pack2(f0.x, f0.y); o.y = pack2(f0.z, f0.w);
    o.z = pack2(f1.x, f1.y); o.w = pack2(f1.z, f1.w);
    ((uint4*)d)[g] = o;
}

// bias arena: [0..2047]=layer0 qkvs, [2048..4095]=layer1 qkvs, [4096..4479]=out
__global__ __launch_bounds__(256)
void pack_bias(const float* q0, const float* k0, const float* v0, const float* s0,
               const float* q1, const float* k1, const float* v1, const float* s1,
               const float* ob, float* __restrict__ dst)
{
    int i = blockIdx.x * 256 + threadIdx.x;
    if (i >= 4480) return;
    float v;
    if (i < 2048) {
        int j = i & 511, q = i >> 9;
        v = (q == 0 ? q0 : q == 1 ? k0 : q == 2 ? v0 : s0)[j];
    } else if (i < 4096) {
        int j = i - 2048; int q = j >> 9; j &= 511;
        v = (q == 0 ? q1 : q == 1 ? k1 : q == 2 ? v1 : s1)[j];
    } else {
        v = ob[i - 4096];
    }
    dst[i] = v;
}

// ---------------------------------------------------------------------------
// CSR build (order within bucket nondeterministic -> only permutes fp adds)
// ---------------------------------------------------------------------------
__global__ __launch_bounds__(256)
void zero_deg(int* __restrict__ deg)
{
    int i = blockIdx.x * 256 + threadIdx.x;
    if (i < NN) deg[i] = 0;
}

__global__ __launch_bounds__(256)
void hist_dst(const int* __restrict__ dst, int* __restrict__ deg)
{
    int e = blockIdx.x * 256 + threadIdx.x;
    if (e < NE) atomicAdd(&deg[dst[e]], 1);
}

// single-block scan, wave-shfl based
__global__ __launch_bounds__(1024)
void scan_deg(const int* __restrict__ deg, int* __restrict__ rowptr,
              int* __restrict__ cursor)
{
    __shared__ int wsum[16];
    const int tid = threadIdx.x, lane = tid & 63, wid = tid >> 6;
    int carry = 0;
    for (int base = 0; base < NN; base += 1024) {
        int i = base + tid;
        int orig = (i < NN) ? deg[i] : 0;
        int v = orig;
        #pragma unroll
        for (int off = 1; off < 64; off <<= 1) {
            int t = __shfl_up(v, off, 64);
            if (lane >= off) v += t;
        }
        if (lane == 63) wsum[wid] = v;
        __syncthreads();
        if (wid == 0) {
            int s = (lane < 16) ? wsum[lane] : 0;
            #pragma unroll
            for (int off = 1; off < 16; off <<= 1) {
                int t = __shfl_up(s, off, 16);
                if ((lane & 15) >= off) s += t;
            }
            if (lane < 16) wsum[lane] = s;
        }
        __syncthreads();
        int woff  = (wid == 0) ? 0 : wsum[wid - 1];
        int total = wsum[15];
        int excl  = carry + woff + (v - orig);
        if (i < NN) { rowptr[i] = excl; cursor[i] = excl; }
        carry += total;
        __syncthreads();
    }
    if (tid == 0) rowptr[NN] = NE;
}

__global__ __launch_bounds__(256)
void scatter_edges(const int* __restrict__ src, const int* __restrict__ dst,
                   int* __restrict__ cursor, int* __restrict__ esrc_ord)
{
    int e = blockIdx.x * 256 + threadIdx.x;
    if (e >= NE) return;
    int pos = atomicAdd(&cursor[dst[e]], 1);
    esrc_ord[pos] = src[e];
}

// ---------------------------------------------------------------------------
// Fused per-node attention, 4-edge unrolled + quad prefetch: one wave per dst
// node; online softmax. Four independent shfl-reduce chains per iteration
// overlap their latency. K-regs re-prefetched right after the dots consume
// them; V-regs after the accumulation. All prefetch branches wave-uniform.
// ---------------------------------------------------------------------------
__global__ __launch_bounds__(256)
void node_attn(const u16* __restrict__ Qb, const u16* __restrict__ Kb,
               const u16* __restrict__ Vb, const int* __restrict__ rowptr,
               const int* __restrict__ esrc, const u16* __restrict__ skipb,
               u16* __restrict__ outb)
{
    int d = blockIdx.x * 4 + (threadIdx.x >> 6);
    if (d >= NN) return;
    int lane = threadIdx.x & 63;

    uint4 qv = *((const uint4*)(Qb + (size_t)d * HC) + lane);
    float q[8] = { bflo(qv.x), bfhi(qv.x), bflo(qv.y), bfhi(qv.y),
                   bflo(qv.z), bfhi(qv.z), bflo(qv.w), bfhi(qv.w) };

    int beg = rowptr[d], end = rowptr[d + 1];
    int n = end - beg;
    float m = -INFINITY, den = 0.f;
    float acc[8] = {};

    uint4 k0, k1, k2, k3, v0, v1, v2, v3;
    if (n > 0){ int s = esrc[beg];     k0 = *((const uint4*)(Kb + (size_t)s * HC) + lane);
                                       v0 = *((const uint4*)(Vb + (size_t)s * HC) + lane); }
    if (n > 1){ int s = esrc[beg + 1]; k1 = *((const uint4*)(Kb + (size_t)s * HC) + lane);
                                       v1 = *((const uint4*)(Vb + (size_t)s * HC) + lane); }
    if (n > 2){ int s = esrc[beg + 2]; k2 = *((const uint4*)(Kb + (size_t)s * HC) + lane);
                                       v2 = *((const uint4*)(Vb + (size_t)s * HC) + lane); }
    if (n > 3){ int s = esrc[beg + 3]; k3 = *((const uint4*)(Kb + (size_t)s * HC) + lane);
                                       v3 = *((const uint4*)(Vb + (size_t)s * HC) + lane); }

    auto single = [&](uint4 kk, uint4 vv){
        float s0 = dot8(q, kk);
        #pragma unroll
        for (int off = 1; off < 16; off <<= 1) s0 += __shfl_xor(s0, off, 64);
        float a0 = s0 * 0.08838834764831845f;
        float mnew = fmaxf(m, a0);
        float sc = __expf(m - mnew);
        float p0 = __expf(a0 - mnew);
        den = den * sc + p0;
        acc[0] = acc[0] * sc + p0 * bflo(vv.x);
        acc[1] = acc[1] * sc + p0 * bfhi(vv.x);
        acc[2] = acc[2] * sc + p0 * bflo(vv.y);
        acc[3] = acc[3] * sc + p0 * bfhi(vv.y);
        acc[4] = acc[4] * sc + p0 * bflo(vv.z);
        acc[5] = acc[5] * sc + p0 * bfhi(vv.z);
        acc[6] = acc[6] * sc + p0 * bflo(vv.w);
        acc[7] = acc[7] * sc + p0 * bfhi(vv.w);
        m = mnew;
    };

    int i = beg;
    for (; i + 3 < end; i += 4) {
        float s0 = dot8(q, k0), s1 = dot8(q, k1), s2 = dot8(q, k2), s3 = dot8(q, k3);
        bool h0 = i + 4 < end, h1 = i + 5 < end, h2 = i + 6 < end, h3 = i + 7 < end;
        int sn0 = 0, sn1 = 0, sn2 = 0, sn3 = 0;
        if (h0) sn0 = esrc[i + 4];
        if (h1) sn1 = esrc[i + 5];
        if (h2) sn2 = esrc[i + 6];
        if (h3) sn3 = esrc[i + 7];
        if (h0) k0 = *((const uint4*)(Kb + (size_t)sn0 * HC) + lane);   // k consumed
        if (h1) k1 = *((const uint4*)(Kb + (size_t)sn1 * HC) + lane);
        if (h2) k2 = *((const uint4*)(Kb + (size_t)sn2 * HC) + lane);
        if (h3) k3 = *((const uint4*)(Kb + (size_t)sn3 * HC) + lane);
        #pragma unroll
        for (int off = 1; off < 16; off <<= 1) {   // four chains interleave
            s0 += __shfl_xor(s0, off, 64);
            s1 += __shfl_xor(s1, off, 64);
            s2 += __shfl_xor(s2, off, 64);
            s3 += __shfl_xor(s3, off, 64);
        }
        float a0 = s0 * 0.08838834764831845f;
        float a1 = s1 * 0.08838834764831845f;
        float a2 = s2 * 0.08838834764831845f;
        float a3 = s3 * 0.08838834764831845f;

        float mnew = fmaxf(fmaxf(fmaxf(a0, a1), fmaxf(a2, a3)), m);
        float sc = __expf(m - mnew);
        float p0 = __expf(a0 - mnew), p1 = __expf(a1 - mnew);
        float p2 = __expf(a2 - mnew), p3 = __expf(a3 - mnew);
        den = den * sc + ((p0 + p1) + (p2 + p3));

        acc[0] = acc[0] * sc + p0 * bflo(v0.x) + p1 * bflo(v1.x) + p2 * bflo(v2.x) + p3 * bflo(v3.x);
        acc[1] = acc[1] * sc + p0 * bfhi(v0.x) + p1 * bfhi(v1.x) + p2 * bfhi(v2.x) + p3 * bfhi(v3.x);
        acc[2] = acc[2] * sc + p0 * bflo(v0.y) + p1 * bflo(v1.y) + p2 * bflo(v2.y) + p3 * bflo(v3.y);
        acc[3] = acc[3] * sc + p0 * bfhi(v0.y) + p1 * bfhi(v1.y) + p2 * bfhi(v2.y) + p3 * bfhi(v3.y);
        acc[4] = acc[4] * sc + p0 * bflo(v0.z) + p1 * bflo(v1.z) + p2 * bflo(v2.z) + p3 * bflo(v3.z);
        acc[5] = acc[5] * sc + p0 * bfhi(v0.z) + p1 * bfhi(v1.z) + p2 * bfhi(v2.z) + p3 * bfhi(v3.z);
        acc[6] = acc[6] * sc + p0 * bflo(v0.w) + p1 * bflo(v1.w) + p2 * bflo(v2.w) + p3 * bflo(v3.w);
        acc[7] = acc[7] * sc + p0 * bfhi(v0.w) + p1 * bfhi(v1.w) + p2 * bfhi(v2.w) + p3 * bfhi(v3.w);
        m = mnew;

        if (h0) v0 = *((const uint4*)(Vb + (size_t)sn0 * HC) + lane);   // v consumed
        if (h1) v1 = *((const uint4*)(Vb + (size_t)sn1 * HC) + lane);
        if (h2) v2 = *((const uint4*)(Vb + (size_t)sn2 * HC) + lane);
        if (h3) v3 = *((const uint4*)(Vb + (size_t)sn3 * HC) + lane);
    }
    if (i < end)     single(k0, v0);    // tail: regs hold edges i, i+1, i+2
    if (i + 1 < end) single(k1, v1);
    if (i + 2 < end) single(k2, v2);

    float inv = 1.f / (den + 1e-16f);
    size_t base = (size_t)d * HC + lane * 8;
    uint4 sv = *((const uint4*)(skipb + base));
    float sk[8] = { bflo(sv.x), bfhi(sv.x), bflo(sv.y), bfhi(sv.y),
                    bflo(sv.z), bfhi(sv.z), bflo(sv.w), bfhi(sv.w) };
    uint4 o;
    o.x = pack2(fmaxf(acc[0] * inv + sk[0], 0.f), fmaxf(acc[1] * inv + sk[1], 0.f));
    o.y = pack2(fmaxf(acc[2] * inv + sk[2], 0.f), fmaxf(acc[3] * inv + sk[3], 0.f));
    o.z = pack2(fmaxf(acc[4] * inv + sk[4], 0.f), fmaxf(acc[5] * inv + sk[5], 0.f));
    o.w = pack2(fmaxf(acc[6] * inv + sk[6], 0.f), fmaxf(acc[7] * inv + sk[7], 0.f));
    *(uint4*)(outb + base) = o;
}

// ---------------------------------------------------------------------------
extern "C" void kernel_launch(void* const* d_in, const int* in_sizes, int n_in,
                              void* d_out, int out_size, void* d_ws, size_t ws_size,
                              hipStream_t stream)
{
    const float* x   = (const float*)d_in[0];
    const int* ei    = (const int*)d_in[1];
    const int* esrc  = ei;
    const int* edst  = ei + NE;
    const float* q0w = (const float*)d_in[2];  const float* q0b = (const float*)d_in[3];
    const float* k0w = (const float*)d_in[4];  const float* k0b = (const float*)d_in[5];
    const float* v0w = (const float*)d_in[6];  const float* v0b = (const float*)d_in[7];
    const float* s0w = (const float*)d_in[8];  const float* s0b = (const float*)d_in[9];
    const float* q1w = (const float*)d_in[10]; const float* q1b = (const float*)d_in[11];
    const float* k1w = (const float*)d_in[12]; const float* k1b = (const float*)d_in[13];
    const float* v1w = (const float*)d_in[14]; const float* v1b = (const float*)d_in[15];
    const float* s1w = (const float*)d_in[16]; const float* s1b = (const float*)d_in[17];
    const float* ow  = (const float*)d_in[18]; const float* obs = (const float*)d_in[19];

    // ---- workspace (~247 MB; Q/V/H/S padded to NP rows) ----
    char* p = (char*)d_ws;
    auto take = [&](size_t bytes) { void* r = (void*)p; p += (bytes + 255) & ~(size_t)255; return r; };
    u16*   Qb     = (u16*)take((size_t)NP * HC * 2);       // 51.25 MB
    u16*   Vb     = (u16*)take((size_t)NP * HC * 2);       // 51.25 MB
    u16*   Hb     = (u16*)take((size_t)NP * HC * 2);       // 51.25 MB
    u16*   Sb     = (u16*)take((size_t)NP * HC * 2);       // 51.25 MB (bf16 skip)
    u16*   Xb     = (u16*)take((size_t)NN * DD * 2);       // 38.4 MB (bf16 x)
    u16*   Wc0    = (u16*)take((size_t)2048 * DD * 2);     // 1.57 MB
    u16*   Wc1    = (u16*)take((size_t)2048 * HC * 2);     // 2.10 MB
    u16*   WcO    = (u16*)take((size_t)DD * HC * 2);       // 0.39 MB
    float* barena = (float*)take(4480 * 4);                // 17.9 KB

    // ---- scratch carved from d_out (dead before final GEMM overwrites all) ----
    char* dob = (char*)d_out;
    u16* Kb       = (u16*)dob;                             // 51.25 MB (padded)
    int* deg      = (int*)(dob + 51249152);
    int* rowptr   = (int*)(dob + 51449344);                // NN+1
    int* cursor   = (int*)(dob + 51649536);
    int* esrc_ord = (int*)(dob + 51849728);                // 1.6 MB (ends 53.5 MB < 76.8)

    dim3 blk(256);
    int gN   = (NN + 255) / 256;
    int gE   = (NE + 255) / 256;
    int gnod = (NN + 3) / 4;
    const int NPAN = (NN + 127) / 128;   // 391 row panels (out-proj)
    int go = NPAN * 3;                   // out-proj: 3 col-tiles

    // ---- prep (2 launches) ----
    pack_bias<<<(4480 + 255) / 256, blk, 0, stream>>>(q0b, k0b, v0b, s0b,
                                                      q1b, k1b, v1b, s1b, obs, barena);
    cvt_all<<<(CVT_TOTAL + 255) / 256, blk, 0, stream>>>(x,
        q0w, k0w, v0w, s0w, q1w, k1w, v1w, s1w, ow, Xb, Wc0, Wc1, WcO);

    // ---- CSR build ----
    zero_deg      <<<gN, blk, 0, stream>>>(deg);
    hist_dst      <<<gE, blk, 0, stream>>>(edst, deg);
    scan_deg      <<<1, 1024, 0, stream>>>(deg, rowptr, cursor);
    scatter_edges <<<gE, blk, 0, stream>>>(esrc, edst, cursor, esrc_ord);

    // ---- layer 0 (A = Xb bf16, K=384) ----
    gemm_ws<DD><<<256, 512, 0, stream>>>(Xb, Wc0, barena, Qb, Kb, Vb, Sb);
    node_attn<<<gnod, blk, 0, stream>>>(Qb, Kb, Vb, rowptr, esrc_ord, Sb, Hb);

    // ---- layer 1 (A = Hb bf16, K=512) ----
    gemm_ws<HC><<<256, 512, 0, stream>>>(Hb, Wc1, barena + 2048, Qb, Kb, Vb, Sb);
    node_attn<<<gnod, blk, 0, stream>>>(Qb, Kb, Vb, rowptr, esrc_ord, Sb, Hb);

    // ---- output projection (fp32 out, overwrites ALL of d_out) ----
    gemm2ph<HC><<<go, blk, 0, stream>>>(Hb, WcO, barena + 4096,
                                        (float*)d_out, NN, 384, 3);
}

// Round 15
// 717.435 us; speedup vs baseline: 1.1011x; 1.1011x over previous
//
#include <hip/hip_runtime.h>
#include <hip/hip_bf16.h>

#define NN 50000   // nodes
#define NE 400000  // edges
#define DD 384     // input dim
#define HC 512     // heads * per-head dim (4 heads x 128)

typedef unsigned int u32;
typedef unsigned short u16;
typedef __attribute__((ext_vector_type(8))) short bf16x8;  // 8 bf16 (4 VGPRs)
typedef __attribute__((ext_vector_type(4))) float f32x4;

#define AS1 __attribute__((address_space(1)))
#define AS3 __attribute__((address_space(3)))

__device__ __forceinline__ float bflo(u32 u){ return __uint_as_float(u << 16); }
__device__ __forceinline__ float bfhi(u32 u){ return __uint_as_float(u & 0xFFFF0000u); }
__device__ __forceinline__ u16 f2bf(float f){
    u32 u = __float_as_uint(f);
    return (u16)((u + 0x7FFFu + ((u >> 16) & 1u)) >> 16);   // RNE
}
__device__ __forceinline__ u32 pack2(float a, float b){
    return (u32)f2bf(a) | ((u32)f2bf(b) << 16);
}
__device__ __forceinline__ float dot8(const float* q, uint4 k){
    return q[0] * bflo(k.x) + q[1] * bfhi(k.x)
         + q[2] * bflo(k.y) + q[3] * bfhi(k.y)
         + q[4] * bflo(k.z) + q[5] * bfhi(k.z)
         + q[6] * bflo(k.w) + q[7] * bfhi(k.w);
}

// ---------------------------------------------------------------------------
// Persistent weight-stationary QKVS GEMM — BYTE-EXACT round-8 version
// (best measured of 6 variants: 176us; r9/r10/r11/r12/r14 redesigns all
// regressed). Grid = 256 blocks (1/CU, 160 KB LDS), 512 threads = 8 waves.
// W[ct*128..+128)[K] staged to LDS ONCE (wide rows, 8-slot XOR window);
// A panels stream through 2x16 KB dbuf with counted vmcnt(2), ~200-step pipe.
// Store "drain" at panel boundaries measured harmless (stores complete into
// L2 fast; r14's reorder to avoid it cost +24%).
// ---------------------------------------------------------------------------
template<int K>
__global__ __launch_bounds__(512)
void gemm_ws(const u16* __restrict__ Ab, const u16* __restrict__ Wb,
             const float* __restrict__ bias,
             u16* __restrict__ oQ, u16* __restrict__ oK,
             u16* __restrict__ oV, u16* __restrict__ oS)
{
    constexpr int NKT  = K / 64;        // A k-chunks per panel
    constexpr int WCH  = K / 8;         // 16B chunks per W row
    constexpr int NPAN = (NN + 127) / 128;
    __shared__ char smW[128 * K * 2];   // 128 KB @K=512, 96 KB @K=384
    __shared__ char smA[2][16384];      // [buf][128 rows][64 k x 2B]

    const int b   = blockIdx.x;
    const int xcd = b & 7;
    const int idx = b >> 3;
    const int ct  = idx & 15;           // col-tile (128 cols of 2048)
    const int rh  = idx >> 4;           // row-half (0/1)

    const int tid  = threadIdx.x;
    const int lane = tid & 63;
    const int w    = tid >> 6;
    const int wq   = w >> 1;            // row quarter 0..3 (32 rows)
    const int wc   = w & 1;             // col half 0..1 (64 cols)
    const int r16  = lane & 15;
    const int kq   = lane >> 4;

    // ---- stage W once ----
    const u16* Wrow0 = Wb + (size_t)ct * 128 * K;
    #pragma unroll
    for (int p = 0; p < (128 * WCH) / 512; ++p) {
        int ci = p * 512 + tid;
        int row = ci / WCH, pc = ci % WCH;
        int lc = (pc & ~7) | ((pc ^ row) & 7);
        __builtin_amdgcn_global_load_lds((const AS1 u32*)(Wrow0 + (size_t)row * K + lc * 8),
                                         (AS3 u32*)(smW + (size_t)ci * 16), 16, 0, 0);
    }

    // ---- panel list: p = (2j+rh)*8 + xcd ----
    auto panel = [&](int j) { return (2 * j + rh) * 8 + xcd; };
    int np = 0;
    while (panel(np) < NPAN) ++np;      // 24 or 25
    const int total = np * NKT;

    // A stage: 1024 chunks over 512 threads -> 2 gload_lds/thread
    auto stageA = [&](int t) {
        int j = t / NKT, kc = t - (t / NKT) * NKT;
        int m0 = panel(j) * 128;
        #pragma unroll
        for (int p = 0; p < 2; ++p) {
            int ci = p * 512 + tid;
            int row = ci >> 3, pc = ci & 7;
            int lc = pc ^ (row & 7);
            int gr = m0 + row; if (gr >= NN) gr = NN - 1;
            __builtin_amdgcn_global_load_lds((const AS1 u32*)(Ab + (size_t)gr * K + kc * 64 + lc * 8),
                                             (AS3 u32*)(smA[t & 1] + ci * 16), 16, 0, 0);
        }
    };

    stageA(0);
    stageA(1);

    f32x4 acc[2][4] = {};

    const int qsel = ct >> 2;
    u16* outp = (qsel == 0) ? oQ : (qsel == 1) ? oK : (qsel == 2) ? oV : oS;
    const int cb = (ct & 3) * 128 + wc * 64;
    float bv4[4];
    #pragma unroll
    for (int ni = 0; ni < 4; ++ni) bv4[ni] = bias[ct * 128 + wc * 64 + ni * 16 + r16];

    for (int t = 0; t < total; ++t) {
        if (t + 1 < total) { asm volatile("s_waitcnt vmcnt(2)" ::: "memory"); }
        else               { asm volatile("s_waitcnt vmcnt(0)" ::: "memory"); }
        __builtin_amdgcn_s_barrier();          // stage(t) landed for all waves
        __builtin_amdgcn_sched_barrier(0);

        const int jj = t / NKT;
        const int kt = t - jj * NKT;
        const char* bufA = smA[t & 1];
        #pragma unroll
        for (int kk = 0; kk < 2; ++kk) {
            bf16x8 av[2], bv[4];
            #pragma unroll
            for (int i = 0; i < 2; ++i) {
                int rowA = wq * 32 + i * 16 + r16;
                int c = kk * 4 + kq;
                av[i] = *(const bf16x8*)(bufA + rowA * 128 + ((c ^ (rowA & 7)) << 4));
            }
            #pragma unroll
            for (int i = 0; i < 4; ++i) {
                int rowW = wc * 64 + i * 16 + r16;
                int c = kt * 8 + kk * 4 + kq;
                int pcw = (c & ~7) | ((c ^ rowW) & 7);
                bv[i] = *(const bf16x8*)(smW + (size_t)rowW * (K * 2) + (pcw << 4));
            }
            #pragma unroll
            for (int mi = 0; mi < 2; ++mi)
                #pragma unroll
                for (int ni = 0; ni < 4; ++ni)
                    acc[mi][ni] = __builtin_amdgcn_mfma_f32_16x16x32_bf16(
                        av[mi], bv[ni], acc[mi][ni], 0, 0, 0);
        }

        __builtin_amdgcn_sched_barrier(0);
        __builtin_amdgcn_s_barrier();          // all waves done reading buf t&1
        __builtin_amdgcn_sched_barrier(0);

        if (kt == NKT - 1) {                   // panel finished: epilogue
            int m0 = panel(jj) * 128;
            #pragma unroll
            for (int ni = 0; ni < 4; ++ni) {
                int col = cb + ni * 16 + r16;
                float bb = bv4[ni];
                #pragma unroll
                for (int mi = 0; mi < 2; ++mi)
                    #pragma unroll
                    for (int r = 0; r < 4; ++r) {
                        int gr = m0 + wq * 32 + mi * 16 + kq * 4 + r;
                        if (gr < NN) outp[(size_t)gr * 512 + col] = f2bf(acc[mi][ni][r] + bb);
                        acc[mi][ni][r] = 0.f;
                    }
            }
        }
        if (t + 2 < total) stageA(t + 2);      // overwrite now-free buffer
    }
}

// ---------------------------------------------------------------------------
// 2-deep pipelined MFMA GEMM — output projection (r7-proven form).
// ---------------------------------------------------------------------------
template<int K>
__global__ __launch_bounds__(256)
void gemm2ph(const u16* __restrict__ Ab, const u16* __restrict__ Wb,
             const float* __restrict__ bias, float* __restrict__ oF,
             int n, int Ototal, int NT)
{
    constexpr int NKT = K / 64;
    __shared__ char smA[2][16384];
    __shared__ char smB[2][16384];

    const int nb  = gridDim.x;
    const int bd  = blockIdx.x;
    const int q8  = nb >> 3, r8 = nb & 7;
    const int xcd = bd & 7, gg = bd >> 3;
    const int tt  = (xcd < r8 ? xcd * (q8 + 1) : r8 * (q8 + 1) + (xcd - r8) * q8) + gg;
    const int m0  = (tt / NT) * 128;
    const int o0  = (tt % NT) * 128;

    const int tid  = threadIdx.x;
    const int lane = tid & 63;
    const int w    = tid >> 6;
    const int wr   = w >> 1, wc = w & 1;
    const int r16  = lane & 15;
    const int kq   = lane >> 4;
    const int swz  = (r16 & 7) << 4;

    auto stage = [&](int bf, int kt) {
        #pragma unroll
        for (int p = 0; p < 4; ++p) {
            int ci = p * 256 + tid, row = ci >> 3, pc = ci & 7;
            int lc = pc ^ (row & 7);
            const u16* g = Wb + (size_t)(o0 + row) * K + kt * 64 + lc * 8;
            __builtin_amdgcn_global_load_lds((const AS1 u32*)g,
                                             (AS3 u32*)(smB[bf] + ci * 16), 16, 0, 0);
        }
        #pragma unroll
        for (int p = 0; p < 4; ++p) {
            int ci = p * 256 + tid, row = ci >> 3, pc = ci & 7;
            int lc = pc ^ (row & 7);
            int gr = m0 + row; if (gr >= n) gr = n - 1;
            const u16* g = Ab + (size_t)gr * K + kt * 64 + lc * 8;
            __builtin_amdgcn_global_load_lds((const AS1 u32*)g,
                                             (AS3 u32*)(smA[bf] + ci * 16), 16, 0, 0);
        }
    };

    f32x4 acc[4][4] = {};

    stage(0, 0);
    stage(1, 1);

    for (int kt = 0; kt < NKT; ++kt) {
        if (kt + 1 < NKT) { asm volatile("s_waitcnt vmcnt(8)" ::: "memory"); }
        else             { asm volatile("s_waitcnt vmcnt(0)" ::: "memory"); }
        __builtin_amdgcn_s_barrier();
        __builtin_amdgcn_sched_barrier(0);

        const char* pa = smA[kt & 1] + (wr * 64) * 128;
        const char* pb = smB[kt & 1] + (wc * 64) * 128;
        #pragma unroll
        for (int kk = 0; kk < 2; ++kk) {
            const int kb = kk * 64 + kq * 16;
            bf16x8 av[4], bv[4];
            #pragma unroll
            for (int i = 0; i < 4; ++i) {
                av[i] = *(const bf16x8*)(pa + (i * 16 + r16) * 128 + (kb ^ swz));
                bv[i] = *(const bf16x8*)(pb + (i * 16 + r16) * 128 + (kb ^ swz));
            }
            #pragma unroll
            for (int mi = 0; mi < 4; ++mi)
                #pragma unroll
                for (int ni = 0; ni < 4; ++ni)
                    acc[mi][ni] = __builtin_amdgcn_mfma_f32_16x16x32_bf16(
                        av[mi], bv[ni], acc[mi][ni], 0, 0, 0);
        }

        __builtin_amdgcn_sched_barrier(0);
        __builtin_amdgcn_s_barrier();
        __builtin_amdgcn_sched_barrier(0);
        if (kt + 2 < NKT) stage(kt & 1, kt + 2);
    }

    const int cbo = o0 + wc * 64;
    #pragma unroll
    for (int ni = 0; ni < 4; ++ni) {
        int col = cbo + ni * 16 + r16;
        float bb = bias[col];
        #pragma unroll
        for (int mi = 0; mi < 4; ++mi)
            #pragma unroll
            for (int r = 0; r < 4; ++r) {
                int gr = m0 + wr * 64 + mi * 16 + kq * 4 + r;
                if (gr < n) oF[(size_t)gr * Ototal + col] = acc[mi][ni][r] + bb;
            }
    }
}

// ---------------------------------------------------------------------------
// Fused fp32 -> bf16 conversion of x + all 9 weight matrices (one launch).
#define XG  2400000      // 50000*384/8
#define W0G 24576        // 512*384/8 per matrix
#define W1G 32768        // 512*512/8 per matrix
#define WOG 24576        // 384*512/8
#define CVT_TOTAL (XG + 4*W0G + 4*W1G + WOG)

__global__ __launch_bounds__(256)
void cvt_all(const float* __restrict__ x,
             const float* q0w, const float* k0w, const float* v0w, const float* s0w,
             const float* q1w, const float* k1w, const float* v1w, const float* s1w,
             const float* ow,
             u16* __restrict__ Xb, u16* __restrict__ Wc0,
             u16* __restrict__ Wc1, u16* __restrict__ WcO)
{
    int i = blockIdx.x * 256 + threadIdx.x;
    if (i >= CVT_TOTAL) return;
    const float* s; u16* d; int g;
    if (i < XG) { s = x; d = Xb; g = i; }
    else {
        int j = i - XG;
        if (j < 4 * W0G) {
            int q = j / W0G; g = j - q * W0G;
            s = (q == 0 ? q0w : q == 1 ? k0w : q == 2 ? v0w : s0w);
            d = Wc0 + (size_t)q * W0G * 8;
        } else if ((j -= 4 * W0G) < 4 * W1G) {
            int q = j / W1G; g = j - q * W1G;
            s = (q == 0 ? q1w : q == 1 ? k1w : q == 2 ? v1w : s1w);
            d = Wc1 + (size_t)q * W1G * 8;
        } else { j -= 4 * W1G; s = ow; d = WcO; g = j; }
    }
    float4 f0 = ((const float4*)s)[(size_t)g * 2];
    float4 f1 = ((const float4*)s)[(size_t)g * 2 + 1];
    uint4 o;
    o.x = pack2(f0.x, f0.y); o.y = pack2(f0.z, f0.w);
    o.z = pack2(f1.x, f1.y); o.w = pack2(f1.z, f1.w);
    ((uint4*)d)[g] = o;
}

// bias arena: [0..2047]=layer0 qkvs, [2048..4095]=layer1 qkvs, [4096..4479]=out
__global__ __launch_bounds__(256)
void pack_bias(const float* q0, const float* k0, const float* v0, const float* s0,
               const float* q1, const float* k1, const float* v1, const float* s1,
               const float* ob, float* __restrict__ dst)
{
    int i = blockIdx.x * 256 + threadIdx.x;
    if (i >= 4480) return;
    float v;
    if (i < 2048) {
        int j = i & 511, q = i >> 9;
        v = (q == 0 ? q0 : q == 1 ? k0 : q == 2 ? v0 : s0)[j];
    } else if (i < 4096) {
        int j = i - 2048; int q = j >> 9; j &= 511;
        v = (q == 0 ? q1 : q == 1 ? k1 : q == 2 ? v1 : s1)[j];
    } else {
        v = ob[i - 4096];
    }
    dst[i] = v;
}

// ---------------------------------------------------------------------------
// CSR build (order within bucket nondeterministic -> only permutes fp adds)
// ---------------------------------------------------------------------------
__global__ __launch_bounds__(256)
void zero_deg(int* __restrict__ deg)
{
    int i = blockIdx.x * 256 + threadIdx.x;
    if (i < NN) deg[i] = 0;
}

__global__ __launch_bounds__(256)
void hist_dst(const int* __restrict__ dst, int* __restrict__ deg)
{
    int e = blockIdx.x * 256 + threadIdx.x;
    if (e < NE) atomicAdd(&deg[dst[e]], 1);
}

// single-block scan, wave-shfl based
__global__ __launch_bounds__(1024)
void scan_deg(const int* __restrict__ deg, int* __restrict__ rowptr,
              int* __restrict__ cursor)
{
    __shared__ int wsum[16];
    const int tid = threadIdx.x, lane = tid & 63, wid = tid >> 6;
    int carry = 0;
    for (int base = 0; base < NN; base += 1024) {
        int i = base + tid;
        int orig = (i < NN) ? deg[i] : 0;
        int v = orig;
        #pragma unroll
        for (int off = 1; off < 64; off <<= 1) {
            int t = __shfl_up(v, off, 64);
            if (lane >= off) v += t;
        }
        if (lane == 63) wsum[wid] = v;
        __syncthreads();
        if (wid == 0) {
            int s = (lane < 16) ? wsum[lane] : 0;
            #pragma unroll
            for (int off = 1; off < 16; off <<= 1) {
                int t = __shfl_up(s, off, 16);
                if ((lane & 15) >= off) s += t;
            }
            if (lane < 16) wsum[lane] = s;
        }
        __syncthreads();
        int woff  = (wid == 0) ? 0 : wsum[wid - 1];
        int total = wsum[15];
        int excl  = carry + woff + (v - orig);
        if (i < NN) { rowptr[i] = excl; cursor[i] = excl; }
        carry += total;
        __syncthreads();
    }
    if (tid == 0) rowptr[NN] = NE;
}

__global__ __launch_bounds__(256)
void scatter_edges(const int* __restrict__ src, const int* __restrict__ dst,
                   int* __restrict__ cursor, int* __restrict__ esrc_ord)
{
    int e = blockIdx.x * 256 + threadIdx.x;
    if (e >= NE) return;
    int pos = atomicAdd(&cursor[dst[e]], 1);
    esrc_ord[pos] = src[e];
}

// ---------------------------------------------------------------------------
// Fused per-node attention, 2-edge unrolled + pair prefetch: one wave per dst
// node; online softmax. Two independent shfl-reduce chains per iteration
// overlap their latency; K/V rows of the NEXT pair load during compute.
// ---------------------------------------------------------------------------
__global__ __launch_bounds__(256)
void node_attn(const u16* __restrict__ Qb, const u16* __restrict__ Kb,
               const u16* __restrict__ Vb, const int* __restrict__ rowptr,
               const int* __restrict__ esrc, const u16* __restrict__ skipb,
               u16* __restrict__ outb)
{
    int d = blockIdx.x * 4 + (threadIdx.x >> 6);
    if (d >= NN) return;
    int lane = threadIdx.x & 63;

    uint4 qv = *((const uint4*)(Qb + (size_t)d * HC) + lane);
    float q[8] = { bflo(qv.x), bfhi(qv.x), bflo(qv.y), bfhi(qv.y),
                   bflo(qv.z), bfhi(qv.z), bflo(qv.w), bfhi(qv.w) };

    int beg = rowptr[d], end = rowptr[d + 1];
    int cnt = end - beg;
    float m = -INFINITY, den = 0.f;
    float acc[8] = {};

    uint4 k0, v0, k1, v1;
    if (cnt > 0) {
        int s = esrc[beg];
        k0 = *((const uint4*)(Kb + (size_t)s * HC) + lane);
        v0 = *((const uint4*)(Vb + (size_t)s * HC) + lane);
    }
    if (cnt > 1) {
        int s = esrc[beg + 1];
        k1 = *((const uint4*)(Kb + (size_t)s * HC) + lane);
        v1 = *((const uint4*)(Vb + (size_t)s * HC) + lane);
    }

    int i = beg;
    for (; i + 1 < end; i += 2) {
        uint4 ka = k0, va = v0, kb = k1, vb = v1;
        if (i + 2 < end) {                       // prefetch next pair
            int s = esrc[i + 2];
            k0 = *((const uint4*)(Kb + (size_t)s * HC) + lane);
            v0 = *((const uint4*)(Vb + (size_t)s * HC) + lane);
        }
        if (i + 3 < end) {
            int s = esrc[i + 3];
            k1 = *((const uint4*)(Kb + (size_t)s * HC) + lane);
            v1 = *((const uint4*)(Vb + (size_t)s * HC) + lane);
        }
        float s0 = dot8(q, ka);
        float s1 = dot8(q, kb);
        #pragma unroll
        for (int off = 1; off < 16; off <<= 1) {   // two chains interleave
            s0 += __shfl_xor(s0, off, 64);
            s1 += __shfl_xor(s1, off, 64);
        }
        float a0 = s0 * 0.08838834764831845f;
        float a1 = s1 * 0.08838834764831845f;

        float mnew  = fmaxf(m, fmaxf(a0, a1));
        float scale = __expf(m - mnew);
        float p0    = __expf(a0 - mnew);
        float p1    = __expf(a1 - mnew);
        den = den * scale + p0 + p1;

        acc[0] = acc[0] * scale + p0 * bflo(va.x) + p1 * bflo(vb.x);
        acc[1] = acc[1] * scale + p0 * bfhi(va.x) + p1 * bfhi(vb.x);
        acc[2] = acc[2] * scale + p0 * bflo(va.y) + p1 * bflo(vb.y);
        acc[3] = acc[3] * scale + p0 * bfhi(va.y) + p1 * bfhi(vb.y);
        acc[4] = acc[4] * scale + p0 * bflo(va.z) + p1 * bflo(vb.z);
        acc[5] = acc[5] * scale + p0 * bfhi(va.z) + p1 * bfhi(vb.z);
        acc[6] = acc[6] * scale + p0 * bflo(va.w) + p1 * bflo(vb.w);
        acc[7] = acc[7] * scale + p0 * bfhi(va.w) + p1 * bfhi(vb.w);
        m = mnew;
    }
    if (i < end) {                               // odd tail: edge lives in k0/v0
        float s0 = dot8(q, k0);
        #pragma unroll
        for (int off = 1; off < 16; off <<= 1) s0 += __shfl_xor(s0, off, 64);
        float a0 = s0 * 0.08838834764831845f;
        float mnew  = fmaxf(m, a0);
        float scale = __expf(m - mnew);
        float p0    = __expf(a0 - mnew);
        den = den * scale + p0;
        acc[0] = acc[0] * scale + p0 * bflo(v0.x);
        acc[1] = acc[1] * scale + p0 * bfhi(v0.x);
        acc[2] = acc[2] * scale + p0 * bflo(v0.y);
        acc[3] = acc[3] * scale + p0 * bfhi(v0.y);
        acc[4] = acc[4] * scale + p0 * bflo(v0.z);
        acc[5] = acc[5] * scale + p0 * bfhi(v0.z);
        acc[6] = acc[6] * scale + p0 * bflo(v0.w);
        acc[7] = acc[7] * scale + p0 * bfhi(v0.w);
    }

    float inv = 1.f / (den + 1e-16f);
    size_t base = (size_t)d * HC + lane * 8;
    uint4 sv = *((const uint4*)(skipb + base));
    float sk[8] = { bflo(sv.x), bfhi(sv.x), bflo(sv.y), bfhi(sv.y),
                    bflo(sv.z), bfhi(sv.z), bflo(sv.w), bfhi(sv.w) };
    uint4 o;
    o.x = pack2(fmaxf(acc[0] * inv + sk[0], 0.f), fmaxf(acc[1] * inv + sk[1], 0.f));
    o.y = pack2(fmaxf(acc[2] * inv + sk[2], 0.f), fmaxf(acc[3] * inv + sk[3], 0.f));
    o.z = pack2(fmaxf(acc[4] * inv + sk[4], 0.f), fmaxf(acc[5] * inv + sk[5], 0.f));
    o.w = pack2(fmaxf(acc[6] * inv + sk[6], 0.f), fmaxf(acc[7] * inv + sk[7], 0.f));
    *(uint4*)(outb + base) = o;
}

// ---------------------------------------------------------------------------
extern "C" void kernel_launch(void* const* d_in, const int* in_sizes, int n_in,
                              void* d_out, int out_size, void* d_ws, size_t ws_size,
                              hipStream_t stream)
{
    const float* x   = (const float*)d_in[0];
    const int* ei    = (const int*)d_in[1];
    const int* esrc  = ei;
    const int* edst  = ei + NE;
    const float* q0w = (const float*)d_in[2];  const float* q0b = (const float*)d_in[3];
    const float* k0w = (const float*)d_in[4];  const float* k0b = (const float*)d_in[5];
    const float* v0w = (const float*)d_in[6];  const float* v0b = (const float*)d_in[7];
    const float* s0w = (const float*)d_in[8];  const float* s0b = (const float*)d_in[9];
    const float* q1w = (const float*)d_in[10]; const float* q1b = (const float*)d_in[11];
    const float* k1w = (const float*)d_in[12]; const float* k1b = (const float*)d_in[13];
    const float* v1w = (const float*)d_in[14]; const float* v1b = (const float*)d_in[15];
    const float* s1w = (const float*)d_in[16]; const float* s1b = (const float*)d_in[17];
    const float* ow  = (const float*)d_in[18]; const float* obs = (const float*)d_in[19];

    // ---- workspace (~247 MB) ----
    char* p = (char*)d_ws;
    auto take = [&](size_t bytes) { void* r = (void*)p; p += (bytes + 255) & ~(size_t)255; return r; };
    u16*   Qb     = (u16*)take((size_t)NN * HC * 2);       // 51.2 MB
    u16*   Vb     = (u16*)take((size_t)NN * HC * 2);       // 51.2 MB
    u16*   Hb     = (u16*)take((size_t)NN * HC * 2);       // 51.2 MB
    u16*   Sb     = (u16*)take((size_t)NN * HC * 2);       // 51.2 MB (bf16 skip)
    u16*   Xb     = (u16*)take((size_t)NN * DD * 2);       // 38.4 MB (bf16 x)
    u16*   Wc0    = (u16*)take((size_t)2048 * DD * 2);     // 1.57 MB
    u16*   Wc1    = (u16*)take((size_t)2048 * HC * 2);     // 2.10 MB
    u16*   WcO    = (u16*)take((size_t)DD * HC * 2);       // 0.39 MB
    float* barena = (float*)take(4480 * 4);                // 17.9 KB

    // ---- scratch carved from d_out (dead before final GEMM overwrites all) ----
    char* dob = (char*)d_out;
    u16* Kb       = (u16*)dob;                             // 51.2 MB
    int* deg      = (int*)(dob + 51200000);
    int* rowptr   = (int*)(dob + 51400192);                // NN+1
    int* cursor   = (int*)(dob + 51600384);
    int* esrc_ord = (int*)(dob + 51800576);                // 1.6 MB

    dim3 blk(256);
    int gN   = (NN + 255) / 256;
    int gE   = (NE + 255) / 256;
    int gnod = (NN + 3) / 4;
    const int NPAN = (NN + 127) / 128;   // 391 row panels (out-proj)
    int go = NPAN * 3;                   // out-proj: 3 col-tiles

    // ---- prep (2 launches) ----
    pack_bias<<<(4480 + 255) / 256, blk, 0, stream>>>(q0b, k0b, v0b, s0b,
                                                      q1b, k1b, v1b, s1b, obs, barena);
    cvt_all<<<(CVT_TOTAL + 255) / 256, blk, 0, stream>>>(x,
        q0w, k0w, v0w, s0w, q1w, k1w, v1w, s1w, ow, Xb, Wc0, Wc1, WcO);

    // ---- CSR build ----
    zero_deg      <<<gN, blk, 0, stream>>>(deg);
    hist_dst      <<<gE, blk, 0, stream>>>(edst, deg);
    scan_deg      <<<1, 1024, 0, stream>>>(deg, rowptr, cursor);
    scatter_edges <<<gE, blk, 0, stream>>>(esrc, edst, cursor, esrc_ord);

    // ---- layer 0 (A = Xb bf16, K=384) ----
    gemm_ws<DD><<<256, 512, 0, stream>>>(Xb, Wc0, barena, Qb, Kb, Vb, Sb);
    node_attn<<<gnod, blk, 0, stream>>>(Qb, Kb, Vb, rowptr, esrc_ord, Sb, Hb);

    // ---- layer 1 (A = Hb bf16, K=512) ----
    gemm_ws<HC><<<256, 512, 0, stream>>>(Hb, Wc1, barena + 2048, Qb, Kb, Vb, Sb);
    node_attn<<<gnod, blk, 0, stream>>>(Qb, Kb, Vb, rowptr, esrc_ord, Sb, Hb);

    // ---- layer 1 uses same CSR; output projection (fp32, overwrites d_out) ----
    gemm2ph<HC><<<go, blk, 0, stream>>>(Hb, WcO, barena + 4096,
                                        (float*)d_out, NN, 384, 3);
}

// Round 16
// 673.162 us; speedup vs baseline: 1.1736x; 1.0658x over previous
//
#include <hip/hip_runtime.h>
#include <hip/hip_bf16.h>

#define NN 50000   // nodes
#define NE 400000  // edges
#define DD 384     // input dim
#define HC 512     // heads * per-head dim (4 heads x 128)

typedef unsigned int u32;
typedef unsigned short u16;
typedef __attribute__((ext_vector_type(8))) short bf16x8;  // 8 bf16 (4 VGPRs)
typedef __attribute__((ext_vector_type(4))) float f32x4;

#define AS1 __attribute__((address_space(1)))
#define AS3 __attribute__((address_space(3)))

__device__ __forceinline__ float bflo(u32 u){ return __uint_as_float(u << 16); }
__device__ __forceinline__ float bfhi(u32 u){ return __uint_as_float(u & 0xFFFF0000u); }
__device__ __forceinline__ u16 f2bf(float f){
    u32 u = __float_as_uint(f);
    return (u16)((u + 0x7FFFu + ((u >> 16) & 1u)) >> 16);   // RNE
}
__device__ __forceinline__ u32 pack2(float a, float b){
    return (u32)f2bf(a) | ((u32)f2bf(b) << 16);
}
__device__ __forceinline__ float dot8(const float* q, uint4 k){
    return q[0] * bflo(k.x) + q[1] * bfhi(k.x)
         + q[2] * bflo(k.y) + q[3] * bfhi(k.y)
         + q[4] * bflo(k.z) + q[5] * bfhi(k.z)
         + q[6] * bflo(k.w) + q[7] * bfhi(k.w);
}

// ---------------------------------------------------------------------------
// Persistent weight-stationary QKVS GEMM — BYTE-EXACT round-8 version
// (best measured of 6 variants: 176us; all redesigns regressed).
// Grid = 256 blocks (1/CU, 160 KB LDS), 512 threads = 8 waves.
// W[ct*128..+128)[K] staged to LDS ONCE (wide rows, 8-slot XOR window);
// A panels stream through 2x16 KB dbuf with counted vmcnt(2), ~200-step pipe.
// ---------------------------------------------------------------------------
template<int K>
__global__ __launch_bounds__(512)
void gemm_ws(const u16* __restrict__ Ab, const u16* __restrict__ Wb,
             const float* __restrict__ bias,
             u16* __restrict__ oQ, u16* __restrict__ oK,
             u16* __restrict__ oV, u16* __restrict__ oS)
{
    constexpr int NKT  = K / 64;        // A k-chunks per panel
    constexpr int WCH  = K / 8;         // 16B chunks per W row
    constexpr int NPAN = (NN + 127) / 128;
    __shared__ char smW[128 * K * 2];   // 128 KB @K=512, 96 KB @K=384
    __shared__ char smA[2][16384];      // [buf][128 rows][64 k x 2B]

    const int b   = blockIdx.x;
    const int xcd = b & 7;
    const int idx = b >> 3;
    const int ct  = idx & 15;           // col-tile (128 cols of 2048)
    const int rh  = idx >> 4;           // row-half (0/1)

    const int tid  = threadIdx.x;
    const int lane = tid & 63;
    const int w    = tid >> 6;
    const int wq   = w >> 1;            // row quarter 0..3 (32 rows)
    const int wc   = w & 1;             // col half 0..1 (64 cols)
    const int r16  = lane & 15;
    const int kq   = lane >> 4;

    // ---- stage W once ----
    const u16* Wrow0 = Wb + (size_t)ct * 128 * K;
    #pragma unroll
    for (int p = 0; p < (128 * WCH) / 512; ++p) {
        int ci = p * 512 + tid;
        int row = ci / WCH, pc = ci % WCH;
        int lc = (pc & ~7) | ((pc ^ row) & 7);
        __builtin_amdgcn_global_load_lds((const AS1 u32*)(Wrow0 + (size_t)row * K + lc * 8),
                                         (AS3 u32*)(smW + (size_t)ci * 16), 16, 0, 0);
    }

    // ---- panel list: p = (2j+rh)*8 + xcd ----
    auto panel = [&](int j) { return (2 * j + rh) * 8 + xcd; };
    int np = 0;
    while (panel(np) < NPAN) ++np;      // 24 or 25
    const int total = np * NKT;

    // A stage: 1024 chunks over 512 threads -> 2 gload_lds/thread
    auto stageA = [&](int t) {
        int j = t / NKT, kc = t - (t / NKT) * NKT;
        int m0 = panel(j) * 128;
        #pragma unroll
        for (int p = 0; p < 2; ++p) {
            int ci = p * 512 + tid;
            int row = ci >> 3, pc = ci & 7;
            int lc = pc ^ (row & 7);
            int gr = m0 + row; if (gr >= NN) gr = NN - 1;
            __builtin_amdgcn_global_load_lds((const AS1 u32*)(Ab + (size_t)gr * K + kc * 64 + lc * 8),
                                             (AS3 u32*)(smA[t & 1] + ci * 16), 16, 0, 0);
        }
    };

    stageA(0);
    stageA(1);

    f32x4 acc[2][4] = {};

    const int qsel = ct >> 2;
    u16* outp = (qsel == 0) ? oQ : (qsel == 1) ? oK : (qsel == 2) ? oV : oS;
    const int cb = (ct & 3) * 128 + wc * 64;
    float bv4[4];
    #pragma unroll
    for (int ni = 0; ni < 4; ++ni) bv4[ni] = bias[ct * 128 + wc * 64 + ni * 16 + r16];

    for (int t = 0; t < total; ++t) {
        if (t + 1 < total) { asm volatile("s_waitcnt vmcnt(2)" ::: "memory"); }
        else               { asm volatile("s_waitcnt vmcnt(0)" ::: "memory"); }
        __builtin_amdgcn_s_barrier();          // stage(t) landed for all waves
        __builtin_amdgcn_sched_barrier(0);

        const int jj = t / NKT;
        const int kt = t - jj * NKT;
        const char* bufA = smA[t & 1];
        #pragma unroll
        for (int kk = 0; kk < 2; ++kk) {
            bf16x8 av[2], bv[4];
            #pragma unroll
            for (int i = 0; i < 2; ++i) {
                int rowA = wq * 32 + i * 16 + r16;
                int c = kk * 4 + kq;
                av[i] = *(const bf16x8*)(bufA + rowA * 128 + ((c ^ (rowA & 7)) << 4));
            }
            #pragma unroll
            for (int i = 0; i < 4; ++i) {
                int rowW = wc * 64 + i * 16 + r16;
                int c = kt * 8 + kk * 4 + kq;
                int pcw = (c & ~7) | ((c ^ rowW) & 7);
                bv[i] = *(const bf16x8*)(smW + (size_t)rowW * (K * 2) + (pcw << 4));
            }
            #pragma unroll
            for (int mi = 0; mi < 2; ++mi)
                #pragma unroll
                for (int ni = 0; ni < 4; ++ni)
                    acc[mi][ni] = __builtin_amdgcn_mfma_f32_16x16x32_bf16(
                        av[mi], bv[ni], acc[mi][ni], 0, 0, 0);
        }

        __builtin_amdgcn_sched_barrier(0);
        __builtin_amdgcn_s_barrier();          // all waves done reading buf t&1
        __builtin_amdgcn_sched_barrier(0);

        if (kt == NKT - 1) {                   // panel finished: epilogue
            int m0 = panel(jj) * 128;
            #pragma unroll
            for (int ni = 0; ni < 4; ++ni) {
                int col = cb + ni * 16 + r16;
                float bb = bv4[ni];
                #pragma unroll
                for (int mi = 0; mi < 2; ++mi)
                    #pragma unroll
                    for (int r = 0; r < 4; ++r) {
                        int gr = m0 + wq * 32 + mi * 16 + kq * 4 + r;
                        if (gr < NN) outp[(size_t)gr * 512 + col] = f2bf(acc[mi][ni][r] + bb);
                        acc[mi][ni][r] = 0.f;
                    }
            }
        }
        if (t + 2 < total) stageA(t + 2);      // overwrite now-free buffer
    }
}

// ---------------------------------------------------------------------------
// Weight-stationary OUT-PROJECTION (fp32 out, O=384, K=512) — same proven
// engine as gemm_ws. Grid = 240 blocks (8 xcd x 3 ct x 10 row-groups),
// panel(j) = (10j+rh)*8+xcd (bijective over 391 panels), 32-40-step pipeline
// vs gemm2ph's 8 (fill/drain amortized away, W read once).
// ---------------------------------------------------------------------------
__global__ __launch_bounds__(512)
void gemm_ws_f(const u16* __restrict__ Ab, const u16* __restrict__ Wb,
               const float* __restrict__ bias, float* __restrict__ oF)
{
    constexpr int K    = 512;
    constexpr int NKT  = 8;
    constexpr int WCH  = 64;
    constexpr int NPAN = (NN + 127) / 128;   // 391
    __shared__ char smW[128 * K * 2];        // 128 KB
    __shared__ char smA[2][16384];

    const int b   = blockIdx.x;
    const int xcd = b & 7;
    const int idx = b >> 3;                  // 0..29
    const int ct  = idx % 3;                 // col-tile (128 of 384)
    const int rh  = idx / 3;                 // 0..9

    const int tid  = threadIdx.x;
    const int lane = tid & 63;
    const int w    = tid >> 6;
    const int wq   = w >> 1;
    const int wc   = w & 1;
    const int r16  = lane & 15;
    const int kq   = lane >> 4;

    // ---- stage W once ----
    const u16* Wrow0 = Wb + (size_t)ct * 128 * K;
    #pragma unroll
    for (int p = 0; p < (128 * WCH) / 512; ++p) {
        int ci = p * 512 + tid;
        int row = ci / WCH, pc = ci % WCH;
        int lc = (pc & ~7) | ((pc ^ row) & 7);
        __builtin_amdgcn_global_load_lds((const AS1 u32*)(Wrow0 + (size_t)row * K + lc * 8),
                                         (AS3 u32*)(smW + (size_t)ci * 16), 16, 0, 0);
    }

    auto panel = [&](int j) { return (10 * j + rh) * 8 + xcd; };
    int np = 0;
    while (panel(np) < NPAN) ++np;           // 4 or 5
    const int total = np * NKT;

    auto stageA = [&](int t) {
        int j = t / NKT, kc = t - (t / NKT) * NKT;
        int m0 = panel(j) * 128;
        #pragma unroll
        for (int p = 0; p < 2; ++p) {
            int ci = p * 512 + tid;
            int row = ci >> 3, pc = ci & 7;
            int lc = pc ^ (row & 7);
            int gr = m0 + row; if (gr >= NN) gr = NN - 1;
            __builtin_amdgcn_global_load_lds((const AS1 u32*)(Ab + (size_t)gr * K + kc * 64 + lc * 8),
                                             (AS3 u32*)(smA[t & 1] + ci * 16), 16, 0, 0);
        }
    };

    stageA(0);
    stageA(1);

    f32x4 acc[2][4] = {};

    const int cb = ct * 128 + wc * 64;
    float bv4[4];
    #pragma unroll
    for (int ni = 0; ni < 4; ++ni) bv4[ni] = bias[cb + ni * 16 + r16];

    for (int t = 0; t < total; ++t) {
        if (t + 1 < total) { asm volatile("s_waitcnt vmcnt(2)" ::: "memory"); }
        else               { asm volatile("s_waitcnt vmcnt(0)" ::: "memory"); }
        __builtin_amdgcn_s_barrier();
        __builtin_amdgcn_sched_barrier(0);

        const int jj = t / NKT;
        const int kt = t - jj * NKT;
        const char* bufA = smA[t & 1];
        #pragma unroll
        for (int kk = 0; kk < 2; ++kk) {
            bf16x8 av[2], bv[4];
            #pragma unroll
            for (int i = 0; i < 2; ++i) {
                int rowA = wq * 32 + i * 16 + r16;
                int c = kk * 4 + kq;
                av[i] = *(const bf16x8*)(bufA + rowA * 128 + ((c ^ (rowA & 7)) << 4));
            }
            #pragma unroll
            for (int i = 0; i < 4; ++i) {
                int rowW = wc * 64 + i * 16 + r16;
                int c = kt * 8 + kk * 4 + kq;
                int pcw = (c & ~7) | ((c ^ rowW) & 7);
                bv[i] = *(const bf16x8*)(smW + (size_t)rowW * (K * 2) + (pcw << 4));
            }
            #pragma unroll
            for (int mi = 0; mi < 2; ++mi)
                #pragma unroll
                for (int ni = 0; ni < 4; ++ni)
                    acc[mi][ni] = __builtin_amdgcn_mfma_f32_16x16x32_bf16(
                        av[mi], bv[ni], acc[mi][ni], 0, 0, 0);
        }

        __builtin_amdgcn_sched_barrier(0);
        __builtin_amdgcn_s_barrier();
        __builtin_amdgcn_sched_barrier(0);

        if (kt == NKT - 1) {                   // panel finished: fp32 epilogue
            int m0 = panel(jj) * 128;
            #pragma unroll
            for (int ni = 0; ni < 4; ++ni) {
                int col = cb + ni * 16 + r16;
                float bb = bv4[ni];
                #pragma unroll
                for (int mi = 0; mi < 2; ++mi)
                    #pragma unroll
                    for (int r = 0; r < 4; ++r) {
                        int gr = m0 + wq * 32 + mi * 16 + kq * 4 + r;
                        if (gr < NN) oF[(size_t)gr * 384 + col] = acc[mi][ni][r] + bb;
                        acc[mi][ni][r] = 0.f;
                    }
            }
        }
        if (t + 2 < total) stageA(t + 2);
    }
}

// ---------------------------------------------------------------------------
// Fused fp32 -> bf16 conversion of x + all 9 weight matrices (one launch).
#define XG  2400000      // 50000*384/8
#define W0G 24576        // 512*384/8 per matrix
#define W1G 32768        // 512*512/8 per matrix
#define WOG 24576        // 384*512/8
#define CVT_TOTAL (XG + 4*W0G + 4*W1G + WOG)

__global__ __launch_bounds__(256)
void cvt_all(const float* __restrict__ x,
             const float* q0w, const float* k0w, const float* v0w, const float* s0w,
             const float* q1w, const float* k1w, const float* v1w, const float* s1w,
             const float* ow,
             u16* __restrict__ Xb, u16* __restrict__ Wc0,
             u16* __restrict__ Wc1, u16* __restrict__ WcO)
{
    int i = blockIdx.x * 256 + threadIdx.x;
    if (i >= CVT_TOTAL) return;
    const float* s; u16* d; int g;
    if (i < XG) { s = x; d = Xb; g = i; }
    else {
        int j = i - XG;
        if (j < 4 * W0G) {
            int q = j / W0G; g = j - q * W0G;
            s = (q == 0 ? q0w : q == 1 ? k0w : q == 2 ? v0w : s0w);
            d = Wc0 + (size_t)q * W0G * 8;
        } else if ((j -= 4 * W0G) < 4 * W1G) {
            int q = j / W1G; g = j - q * W1G;
            s = (q == 0 ? q1w : q == 1 ? k1w : q == 2 ? v1w : s1w);
            d = Wc1 + (size_t)q * W1G * 8;
        } else { j -= 4 * W1G; s = ow; d = WcO; g = j; }
    }
    float4 f0 = ((const float4*)s)[(size_t)g * 2];
    float4 f1 = ((const float4*)s)[(size_t)g * 2 + 1];
    uint4 o;
    o.x = pack2(f0.x, f0.y); o.y = pack2(f0.z, f0.w);
    o.z = pack2(f1.x, f1.y); o.w = pack2(f1.z, f1.w);
    ((uint4*)d)[g] = o;
}

// bias arena: [0..2047]=layer0 qkvs, [2048..4095]=layer1 qkvs, [4096..4479]=out
__global__ __launch_bounds__(256)
void pack_bias(const float* q0, const float* k0, const float* v0, const float* s0,
               const float* q1, const float* k1, const float* v1, const float* s1,
               const float* ob, float* __restrict__ dst)
{
    int i = blockIdx.x * 256 + threadIdx.x;
    if (i >= 4480) return;
    float v;
    if (i < 2048) {
        int j = i & 511, q = i >> 9;
        v = (q == 0 ? q0 : q == 1 ? k0 : q == 2 ? v0 : s0)[j];
    } else if (i < 4096) {
        int j = i - 2048; int q = j >> 9; j &= 511;
        v = (q == 0 ? q1 : q == 1 ? k1 : q == 2 ? v1 : s1)[j];
    } else {
        v = ob[i - 4096];
    }
    dst[i] = v;
}

// ---------------------------------------------------------------------------
// CSR build (order within bucket nondeterministic -> only permutes fp adds)
// ---------------------------------------------------------------------------
__global__ __launch_bounds__(256)
void zero_deg(int* __restrict__ deg)
{
    int i = blockIdx.x * 256 + threadIdx.x;
    if (i < NN) deg[i] = 0;
}

__global__ __launch_bounds__(256)
void hist_dst(const int* __restrict__ dst, int* __restrict__ deg)
{
    int e = blockIdx.x * 256 + threadIdx.x;
    if (e < NE) atomicAdd(&deg[dst[e]], 1);
}

// single-block scan, 4 elems/thread (13 chunk-iterations instead of 49)
__global__ __launch_bounds__(1024)
void scan_deg(const int* __restrict__ deg, int* __restrict__ rowptr,
              int* __restrict__ cursor)
{
    __shared__ int wsum[16];
    const int tid = threadIdx.x, lane = tid & 63, wid = tid >> 6;
    int carry = 0;
    for (int base = 0; base < NN; base += 4096) {
        int idx = base + tid * 4;
        int4 v4 = make_int4(0, 0, 0, 0);
        if (idx + 3 < NN)      v4 = *(const int4*)(deg + idx);
        else if (idx < NN) {
            v4.x = deg[idx];
            if (idx + 1 < NN) v4.y = deg[idx + 1];
            if (idx + 2 < NN) v4.z = deg[idx + 2];
        }
        int t0 = v4.x, t1 = t0 + v4.y, t2 = t1 + v4.z, t3 = t2 + v4.w;
        int v = t3;                       // per-thread sum
        #pragma unroll
        for (int off = 1; off < 64; off <<= 1) {
            int t = __shfl_up(v, off, 64);
            if (lane >= off) v += t;
        }
        if (lane == 63) wsum[wid] = v;
        __syncthreads();
        if (wid == 0) {
            int s = (lane < 16) ? wsum[lane] : 0;
            #pragma unroll
            for (int off = 1; off < 16; off <<= 1) {
                int t = __shfl_up(s, off, 16);
                if ((lane & 15) >= off) s += t;
            }
            if (lane < 16) wsum[lane] = s;
        }
        __syncthreads();
        int woff  = (wid == 0) ? 0 : wsum[wid - 1];
        int total = wsum[15];
        int texcl = carry + woff + (v - t3);   // exclusive before this thread
        if (idx < NN)     { rowptr[idx]     = texcl;      cursor[idx]     = texcl; }
        if (idx + 1 < NN) { rowptr[idx + 1] = texcl + t0; cursor[idx + 1] = texcl + t0; }
        if (idx + 2 < NN) { rowptr[idx + 2] = texcl + t1; cursor[idx + 2] = texcl + t1; }
        if (idx + 3 < NN) { rowptr[idx + 3] = texcl + t2; cursor[idx + 3] = texcl + t2; }
        carry += total;
        __syncthreads();                     // wsum reused next chunk
    }
    if (tid == 0) rowptr[NN] = NE;
}

__global__ __launch_bounds__(256)
void scatter_edges(const int* __restrict__ src, const int* __restrict__ dst,
                   int* __restrict__ cursor, int* __restrict__ esrc_ord)
{
    int e = blockIdx.x * 256 + threadIdx.x;
    if (e >= NE) return;
    int pos = atomicAdd(&cursor[dst[e]], 1);
    esrc_ord[pos] = src[e];
}

// ---------------------------------------------------------------------------
// Fused per-node attention, 2-edge unrolled + pair prefetch (r13-proven).
// ---------------------------------------------------------------------------
__global__ __launch_bounds__(256)
void node_attn(const u16* __restrict__ Qb, const u16* __restrict__ Kb,
               const u16* __restrict__ Vb, const int* __restrict__ rowptr,
               const int* __restrict__ esrc, const u16* __restrict__ skipb,
               u16* __restrict__ outb)
{
    int d = blockIdx.x * 4 + (threadIdx.x >> 6);
    if (d >= NN) return;
    int lane = threadIdx.x & 63;

    uint4 qv = *((const uint4*)(Qb + (size_t)d * HC) + lane);
    float q[8] = { bflo(qv.x), bfhi(qv.x), bflo(qv.y), bfhi(qv.y),
                   bflo(qv.z), bfhi(qv.z), bflo(qv.w), bfhi(qv.w) };

    int beg = rowptr[d], end = rowptr[d + 1];
    int cnt = end - beg;
    float m = -INFINITY, den = 0.f;
    float acc[8] = {};

    uint4 k0, v0, k1, v1;
    if (cnt > 0) {
        int s = esrc[beg];
        k0 = *((const uint4*)(Kb + (size_t)s * HC) + lane);
        v0 = *((const uint4*)(Vb + (size_t)s * HC) + lane);
    }
    if (cnt > 1) {
        int s = esrc[beg + 1];
        k1 = *((const uint4*)(Kb + (size_t)s * HC) + lane);
        v1 = *((const uint4*)(Vb + (size_t)s * HC) + lane);
    }

    int i = beg;
    for (; i + 1 < end; i += 2) {
        uint4 ka = k0, va = v0, kb = k1, vb = v1;
        if (i + 2 < end) {                       // prefetch next pair
            int s = esrc[i + 2];
            k0 = *((const uint4*)(Kb + (size_t)s * HC) + lane);
            v0 = *((const uint4*)(Vb + (size_t)s * HC) + lane);
        }
        if (i + 3 < end) {
            int s = esrc[i + 3];
            k1 = *((const uint4*)(Kb + (size_t)s * HC) + lane);
            v1 = *((const uint4*)(Vb + (size_t)s * HC) + lane);
        }
        float s0 = dot8(q, ka);
        float s1 = dot8(q, kb);
        #pragma unroll
        for (int off = 1; off < 16; off <<= 1) {   // two chains interleave
            s0 += __shfl_xor(s0, off, 64);
            s1 += __shfl_xor(s1, off, 64);
        }
        float a0 = s0 * 0.08838834764831845f;
        float a1 = s1 * 0.08838834764831845f;

        float mnew  = fmaxf(m, fmaxf(a0, a1));
        float scale = __expf(m - mnew);
        float p0    = __expf(a0 - mnew);
        float p1    = __expf(a1 - mnew);
        den = den * scale + p0 + p1;

        acc[0] = acc[0] * scale + p0 * bflo(va.x) + p1 * bflo(vb.x);
        acc[1] = acc[1] * scale + p0 * bfhi(va.x) + p1 * bfhi(vb.x);
        acc[2] = acc[2] * scale + p0 * bflo(va.y) + p1 * bflo(vb.y);
        acc[3] = acc[3] * scale + p0 * bfhi(va.y) + p1 * bfhi(vb.y);
        acc[4] = acc[4] * scale + p0 * bflo(va.z) + p1 * bflo(vb.z);
        acc[5] = acc[5] * scale + p0 * bfhi(va.z) + p1 * bfhi(vb.z);
        acc[6] = acc[6] * scale + p0 * bflo(va.w) + p1 * bflo(vb.w);
        acc[7] = acc[7] * scale + p0 * bfhi(va.w) + p1 * bfhi(vb.w);
        m = mnew;
    }
    if (i < end) {                               // odd tail: edge lives in k0/v0
        float s0 = dot8(q, k0);
        #pragma unroll
        for (int off = 1; off < 16; off <<= 1) s0 += __shfl_xor(s0, off, 64);
        float a0 = s0 * 0.08838834764831845f;
        float mnew  = fmaxf(m, a0);
        float scale = __expf(m - mnew);
        float p0    = __expf(a0 - mnew);
        den = den * scale + p0;
        acc[0] = acc[0] * scale + p0 * bflo(v0.x);
        acc[1] = acc[1] * scale + p0 * bfhi(v0.x);
        acc[2] = acc[2] * scale + p0 * bflo(v0.y);
        acc[3] = acc[3] * scale + p0 * bfhi(v0.y);
        acc[4] = acc[4] * scale + p0 * bflo(v0.z);
        acc[5] = acc[5] * scale + p0 * bfhi(v0.z);
        acc[6] = acc[6] * scale + p0 * bflo(v0.w);
        acc[7] = acc[7] * scale + p0 * bfhi(v0.w);
    }

    float inv = 1.f / (den + 1e-16f);
    size_t base = (size_t)d * HC + lane * 8;
    uint4 sv = *((const uint4*)(skipb + base));
    float sk[8] = { bflo(sv.x), bfhi(sv.x), bflo(sv.y), bfhi(sv.y),
                    bflo(sv.z), bfhi(sv.z), bflo(sv.w), bfhi(sv.w) };
    uint4 o;
    o.x = pack2(fmaxf(acc[0] * inv + sk[0], 0.f), fmaxf(acc[1] * inv + sk[1], 0.f));
    o.y = pack2(fmaxf(acc[2] * inv + sk[2], 0.f), fmaxf(acc[3] * inv + sk[3], 0.f));
    o.z = pack2(fmaxf(acc[4] * inv + sk[4], 0.f), fmaxf(acc[5] * inv + sk[5], 0.f));
    o.w = pack2(fmaxf(acc[6] * inv + sk[6], 0.f), fmaxf(acc[7] * inv + sk[7], 0.f));
    *(uint4*)(outb + base) = o;
}

// ---------------------------------------------------------------------------
extern "C" void kernel_launch(void* const* d_in, const int* in_sizes, int n_in,
                              void* d_out, int out_size, void* d_ws, size_t ws_size,
                              hipStream_t stream)
{
    const float* x   = (const float*)d_in[0];
    const int* ei    = (const int*)d_in[1];
    const int* esrc  = ei;
    const int* edst  = ei + NE;
    const float* q0w = (const float*)d_in[2];  const float* q0b = (const float*)d_in[3];
    const float* k0w = (const float*)d_in[4];  const float* k0b = (const float*)d_in[5];
    const float* v0w = (const float*)d_in[6];  const float* v0b = (const float*)d_in[7];
    const float* s0w = (const float*)d_in[8];  const float* s0b = (const float*)d_in[9];
    const float* q1w = (const float*)d_in[10]; const float* q1b = (const float*)d_in[11];
    const float* k1w = (const float*)d_in[12]; const float* k1b = (const float*)d_in[13];
    const float* v1w = (const float*)d_in[14]; const float* v1b = (const float*)d_in[15];
    const float* s1w = (const float*)d_in[16]; const float* s1b = (const float*)d_in[17];
    const float* ow  = (const float*)d_in[18]; const float* obs = (const float*)d_in[19];

    // ---- workspace (~247 MB) ----
    char* p = (char*)d_ws;
    auto take = [&](size_t bytes) { void* r = (void*)p; p += (bytes + 255) & ~(size_t)255; return r; };
    u16*   Qb     = (u16*)take((size_t)NN * HC * 2);       // 51.2 MB
    u16*   Vb     = (u16*)take((size_t)NN * HC * 2);       // 51.2 MB
    u16*   Hb     = (u16*)take((size_t)NN * HC * 2);       // 51.2 MB
    u16*   Sb     = (u16*)take((size_t)NN * HC * 2);       // 51.2 MB (bf16 skip)
    u16*   Xb     = (u16*)take((size_t)NN * DD * 2);       // 38.4 MB (bf16 x)
    u16*   Wc0    = (u16*)take((size_t)2048 * DD * 2);     // 1.57 MB
    u16*   Wc1    = (u16*)take((size_t)2048 * HC * 2);     // 2.10 MB
    u16*   WcO    = (u16*)take((size_t)DD * HC * 2);       // 0.39 MB
    float* barena = (float*)take(4480 * 4);                // 17.9 KB

    // ---- scratch carved from d_out (dead before final GEMM overwrites all) ----
    char* dob = (char*)d_out;
    u16* Kb       = (u16*)dob;                             // 51.2 MB
    int* deg      = (int*)(dob + 51200000);
    int* rowptr   = (int*)(dob + 51400192);                // NN+1
    int* cursor   = (int*)(dob + 51600384);
    int* esrc_ord = (int*)(dob + 51800576);                // 1.6 MB

    dim3 blk(256);
    int gN   = (NN + 255) / 256;
    int gE   = (NE + 255) / 256;
    int gnod = (NN + 3) / 4;

    // ---- prep (2 launches) ----
    pack_bias<<<(4480 + 255) / 256, blk, 0, stream>>>(q0b, k0b, v0b, s0b,
                                                      q1b, k1b, v1b, s1b, obs, barena);
    cvt_all<<<(CVT_TOTAL + 255) / 256, blk, 0, stream>>>(x,
        q0w, k0w, v0w, s0w, q1w, k1w, v1w, s1w, ow, Xb, Wc0, Wc1, WcO);

    // ---- CSR build ----
    zero_deg      <<<gN, blk, 0, stream>>>(deg);
    hist_dst      <<<gE, blk, 0, stream>>>(edst, deg);
    scan_deg      <<<1, 1024, 0, stream>>>(deg, rowptr, cursor);
    scatter_edges <<<gE, blk, 0, stream>>>(esrc, edst, cursor, esrc_ord);

    // ---- layer 0 (A = Xb bf16, K=384) ----
    gemm_ws<DD><<<256, 512, 0, stream>>>(Xb, Wc0, barena, Qb, Kb, Vb, Sb);
    node_attn<<<gnod, blk, 0, stream>>>(Qb, Kb, Vb, rowptr, esrc_ord, Sb, Hb);

    // ---- layer 1 (A = Hb bf16, K=512) ----
    gemm_ws<HC><<<256, 512, 0, stream>>>(Hb, Wc1, barena + 2048, Qb, Kb, Vb, Sb);
    node_attn<<<gnod, blk, 0, stream>>>(Qb, Kb, Vb, rowptr, esrc_ord, Sb, Hb);

    // ---- output projection (weight-stationary, fp32, overwrites ALL of d_out) ----
    gemm_ws_f<<<240, 512, 0, stream>>>(Hb, WcO, barena + 4096, (float*)d_out);
}

// Round 17
// 662.478 us; speedup vs baseline: 1.1925x; 1.0161x over previous
//
#include <hip/hip_runtime.h>
#include <hip/hip_bf16.h>

#define NN 50000   // nodes
#define NE 400000  // edges
#define DD 384     // input dim
#define HC 512     // heads * per-head dim (4 heads x 128)

typedef unsigned int u32;
typedef unsigned short u16;
typedef __attribute__((ext_vector_type(8))) short bf16x8;  // 8 bf16 (4 VGPRs)
typedef __attribute__((ext_vector_type(4))) float f32x4;

#define AS1 __attribute__((address_space(1)))
#define AS3 __attribute__((address_space(3)))

__device__ __forceinline__ float bflo(u32 u){ return __uint_as_float(u << 16); }
__device__ __forceinline__ float bfhi(u32 u){ return __uint_as_float(u & 0xFFFF0000u); }
__device__ __forceinline__ u16 f2bf(float f){
    u32 u = __float_as_uint(f);
    return (u16)((u + 0x7FFFu + ((u >> 16) & 1u)) >> 16);   // RNE
}
__device__ __forceinline__ u32 pack2(float a, float b){
    return (u32)f2bf(a) | ((u32)f2bf(b) << 16);
}
__device__ __forceinline__ float dot8(const float* q, uint4 k){
    return q[0] * bflo(k.x) + q[1] * bfhi(k.x)
         + q[2] * bflo(k.y) + q[3] * bfhi(k.y)
         + q[4] * bflo(k.z) + q[5] * bfhi(k.z)
         + q[6] * bflo(k.w) + q[7] * bfhi(k.w);
}

// ---------------------------------------------------------------------------
// Persistent weight-stationary QKVS GEMM — BYTE-EXACT round-8 version
// (best measured of 6 variants: ~175us; all redesigns regressed).
// Grid = 256 blocks (1/CU, 160 KB LDS), 512 threads = 8 waves.
// W[ct*128..+128)[K] staged to LDS ONCE (wide rows, 8-slot XOR window);
// A panels stream through 2x16 KB dbuf with counted vmcnt(2), ~200-step pipe.
// ---------------------------------------------------------------------------
template<int K>
__global__ __launch_bounds__(512)
void gemm_ws(const u16* __restrict__ Ab, const u16* __restrict__ Wb,
             const float* __restrict__ bias,
             u16* __restrict__ oQ, u16* __restrict__ oK,
             u16* __restrict__ oV, u16* __restrict__ oS)
{
    constexpr int NKT  = K / 64;        // A k-chunks per panel
    constexpr int WCH  = K / 8;         // 16B chunks per W row
    constexpr int NPAN = (NN + 127) / 128;
    __shared__ char smW[128 * K * 2];   // 128 KB @K=512, 96 KB @K=384
    __shared__ char smA[2][16384];      // [buf][128 rows][64 k x 2B]

    const int b   = blockIdx.x;
    const int xcd = b & 7;
    const int idx = b >> 3;
    const int ct  = idx & 15;           // col-tile (128 cols of 2048)
    const int rh  = idx >> 4;           // row-half (0/1)

    const int tid  = threadIdx.x;
    const int lane = tid & 63;
    const int w    = tid >> 6;
    const int wq   = w >> 1;            // row quarter 0..3 (32 rows)
    const int wc   = w & 1;             // col half 0..1 (64 cols)
    const int r16  = lane & 15;
    const int kq   = lane >> 4;

    // ---- stage W once ----
    const u16* Wrow0 = Wb + (size_t)ct * 128 * K;
    #pragma unroll
    for (int p = 0; p < (128 * WCH) / 512; ++p) {
        int ci = p * 512 + tid;
        int row = ci / WCH, pc = ci % WCH;
        int lc = (pc & ~7) | ((pc ^ row) & 7);
        __builtin_amdgcn_global_load_lds((const AS1 u32*)(Wrow0 + (size_t)row * K + lc * 8),
                                         (AS3 u32*)(smW + (size_t)ci * 16), 16, 0, 0);
    }

    // ---- panel list: p = (2j+rh)*8 + xcd ----
    auto panel = [&](int j) { return (2 * j + rh) * 8 + xcd; };
    int np = 0;
    while (panel(np) < NPAN) ++np;      // 24 or 25
    const int total = np * NKT;

    // A stage: 1024 chunks over 512 threads -> 2 gload_lds/thread
    auto stageA = [&](int t) {
        int j = t / NKT, kc = t - (t / NKT) * NKT;
        int m0 = panel(j) * 128;
        #pragma unroll
        for (int p = 0; p < 2; ++p) {
            int ci = p * 512 + tid;
            int row = ci >> 3, pc = ci & 7;
            int lc = pc ^ (row & 7);
            int gr = m0 + row; if (gr >= NN) gr = NN - 1;
            __builtin_amdgcn_global_load_lds((const AS1 u32*)(Ab + (size_t)gr * K + kc * 64 + lc * 8),
                                             (AS3 u32*)(smA[t & 1] + ci * 16), 16, 0, 0);
        }
    };

    stageA(0);
    stageA(1);

    f32x4 acc[2][4] = {};

    const int qsel = ct >> 2;
    u16* outp = (qsel == 0) ? oQ : (qsel == 1) ? oK : (qsel == 2) ? oV : oS;
    const int cb = (ct & 3) * 128 + wc * 64;
    float bv4[4];
    #pragma unroll
    for (int ni = 0; ni < 4; ++ni) bv4[ni] = bias[ct * 128 + wc * 64 + ni * 16 + r16];

    for (int t = 0; t < total; ++t) {
        if (t + 1 < total) { asm volatile("s_waitcnt vmcnt(2)" ::: "memory"); }
        else               { asm volatile("s_waitcnt vmcnt(0)" ::: "memory"); }
        __builtin_amdgcn_s_barrier();          // stage(t) landed for all waves
        __builtin_amdgcn_sched_barrier(0);

        const int jj = t / NKT;
        const int kt = t - jj * NKT;
        const char* bufA = smA[t & 1];
        #pragma unroll
        for (int kk = 0; kk < 2; ++kk) {
            bf16x8 av[2], bv[4];
            #pragma unroll
            for (int i = 0; i < 2; ++i) {
                int rowA = wq * 32 + i * 16 + r16;
                int c = kk * 4 + kq;
                av[i] = *(const bf16x8*)(bufA + rowA * 128 + ((c ^ (rowA & 7)) << 4));
            }
            #pragma unroll
            for (int i = 0; i < 4; ++i) {
                int rowW = wc * 64 + i * 16 + r16;
                int c = kt * 8 + kk * 4 + kq;
                int pcw = (c & ~7) | ((c ^ rowW) & 7);
                bv[i] = *(const bf16x8*)(smW + (size_t)rowW * (K * 2) + (pcw << 4));
            }
            #pragma unroll
            for (int mi = 0; mi < 2; ++mi)
                #pragma unroll
                for (int ni = 0; ni < 4; ++ni)
                    acc[mi][ni] = __builtin_amdgcn_mfma_f32_16x16x32_bf16(
                        av[mi], bv[ni], acc[mi][ni], 0, 0, 0);
        }

        __builtin_amdgcn_sched_barrier(0);
        __builtin_amdgcn_s_barrier();          // all waves done reading buf t&1
        __builtin_amdgcn_sched_barrier(0);

        if (kt == NKT - 1) {                   // panel finished: epilogue
            int m0 = panel(jj) * 128;
            #pragma unroll
            for (int ni = 0; ni < 4; ++ni) {
                int col = cb + ni * 16 + r16;
                float bb = bv4[ni];
                #pragma unroll
                for (int mi = 0; mi < 2; ++mi)
                    #pragma unroll
                    for (int r = 0; r < 4; ++r) {
                        int gr = m0 + wq * 32 + mi * 16 + kq * 4 + r;
                        if (gr < NN) outp[(size_t)gr * 512 + col] = f2bf(acc[mi][ni][r] + bb);
                        acc[mi][ni][r] = 0.f;
                    }
            }
        }
        if (t + 2 < total) stageA(t + 2);      // overwrite now-free buffer
    }
}

// ---------------------------------------------------------------------------
// Weight-stationary OUT-PROJECTION (fp32 out, O=384, K=512) — r16-proven.
// Grid = 240 blocks (8 xcd x 3 ct x 10 row-groups), 32-40-step pipeline.
// ---------------------------------------------------------------------------
__global__ __launch_bounds__(512)
void gemm_ws_f(const u16* __restrict__ Ab, const u16* __restrict__ Wb,
               const float* __restrict__ bias, float* __restrict__ oF)
{
    constexpr int K    = 512;
    constexpr int NKT  = 8;
    constexpr int WCH  = 64;
    constexpr int NPAN = (NN + 127) / 128;   // 391
    __shared__ char smW[128 * K * 2];        // 128 KB
    __shared__ char smA[2][16384];

    const int b   = blockIdx.x;
    const int xcd = b & 7;
    const int idx = b >> 3;                  // 0..29
    const int ct  = idx % 3;                 // col-tile (128 of 384)
    const int rh  = idx / 3;                 // 0..9

    const int tid  = threadIdx.x;
    const int lane = tid & 63;
    const int w    = tid >> 6;
    const int wq   = w >> 1;
    const int wc   = w & 1;
    const int r16  = lane & 15;
    const int kq   = lane >> 4;

    const u16* Wrow0 = Wb + (size_t)ct * 128 * K;
    #pragma unroll
    for (int p = 0; p < (128 * WCH) / 512; ++p) {
        int ci = p * 512 + tid;
        int row = ci / WCH, pc = ci % WCH;
        int lc = (pc & ~7) | ((pc ^ row) & 7);
        __builtin_amdgcn_global_load_lds((const AS1 u32*)(Wrow0 + (size_t)row * K + lc * 8),
                                         (AS3 u32*)(smW + (size_t)ci * 16), 16, 0, 0);
    }

    auto panel = [&](int j) { return (10 * j + rh) * 8 + xcd; };
    int np = 0;
    while (panel(np) < NPAN) ++np;           // 4 or 5
    const int total = np * NKT;

    auto stageA = [&](int t) {
        int j = t / NKT, kc = t - (t / NKT) * NKT;
        int m0 = panel(j) * 128;
        #pragma unroll
        for (int p = 0; p < 2; ++p) {
            int ci = p * 512 + tid;
            int row = ci >> 3, pc = ci & 7;
            int lc = pc ^ (row & 7);
            int gr = m0 + row; if (gr >= NN) gr = NN - 1;
            __builtin_amdgcn_global_load_lds((const AS1 u32*)(Ab + (size_t)gr * K + kc * 64 + lc * 8),
                                             (AS3 u32*)(smA[t & 1] + ci * 16), 16, 0, 0);
        }
    };

    stageA(0);
    stageA(1);

    f32x4 acc[2][4] = {};

    const int cb = ct * 128 + wc * 64;
    float bv4[4];
    #pragma unroll
    for (int ni = 0; ni < 4; ++ni) bv4[ni] = bias[cb + ni * 16 + r16];

    for (int t = 0; t < total; ++t) {
        if (t + 1 < total) { asm volatile("s_waitcnt vmcnt(2)" ::: "memory"); }
        else               { asm volatile("s_waitcnt vmcnt(0)" ::: "memory"); }
        __builtin_amdgcn_s_barrier();
        __builtin_amdgcn_sched_barrier(0);

        const int jj = t / NKT;
        const int kt = t - jj * NKT;
        const char* bufA = smA[t & 1];
        #pragma unroll
        for (int kk = 0; kk < 2; ++kk) {
            bf16x8 av[2], bv[4];
            #pragma unroll
            for (int i = 0; i < 2; ++i) {
                int rowA = wq * 32 + i * 16 + r16;
                int c = kk * 4 + kq;
                av[i] = *(const bf16x8*)(bufA + rowA * 128 + ((c ^ (rowA & 7)) << 4));
            }
            #pragma unroll
            for (int i = 0; i < 4; ++i) {
                int rowW = wc * 64 + i * 16 + r16;
                int c = kt * 8 + kk * 4 + kq;
                int pcw = (c & ~7) | ((c ^ rowW) & 7);
                bv[i] = *(const bf16x8*)(smW + (size_t)rowW * (K * 2) + (pcw << 4));
            }
            #pragma unroll
            for (int mi = 0; mi < 2; ++mi)
                #pragma unroll
                for (int ni = 0; ni < 4; ++ni)
                    acc[mi][ni] = __builtin_amdgcn_mfma_f32_16x16x32_bf16(
                        av[mi], bv[ni], acc[mi][ni], 0, 0, 0);
        }

        __builtin_amdgcn_sched_barrier(0);
        __builtin_amdgcn_s_barrier();
        __builtin_amdgcn_sched_barrier(0);

        if (kt == NKT - 1) {                   // panel finished: fp32 epilogue
            int m0 = panel(jj) * 128;
            #pragma unroll
            for (int ni = 0; ni < 4; ++ni) {
                int col = cb + ni * 16 + r16;
                float bb = bv4[ni];
                #pragma unroll
                for (int mi = 0; mi < 2; ++mi)
                    #pragma unroll
                    for (int r = 0; r < 4; ++r) {
                        int gr = m0 + wq * 32 + mi * 16 + kq * 4 + r;
                        if (gr < NN) oF[(size_t)gr * 384 + col] = acc[mi][ni][r] + bb;
                        acc[mi][ni][r] = 0.f;
                    }
            }
        }
        if (t + 2 < total) stageA(t + 2);
    }
}

// ---------------------------------------------------------------------------
// Fused prep: fp32->bf16 conversion of x + 9 weight matrices, PLUS the
// 4480-float bias arena, in ONE launch.
#define XG  2400000      // 50000*384/8
#define W0G 24576        // 512*384/8 per matrix
#define W1G 32768        // 512*512/8 per matrix
#define WOG 24576        // 384*512/8
#define CVT_TOTAL (XG + 4*W0G + 4*W1G + WOG)
#define PREP_TOTAL (CVT_TOTAL + 4480)

__global__ __launch_bounds__(256)
void prep_all(const float* __restrict__ x,
              const float* q0w, const float* k0w, const float* v0w, const float* s0w,
              const float* q1w, const float* k1w, const float* v1w, const float* s1w,
              const float* ow,
              const float* q0b, const float* k0b, const float* v0b, const float* s0b,
              const float* q1b, const float* k1b, const float* v1b, const float* s1b,
              const float* ob,
              u16* __restrict__ Xb, u16* __restrict__ Wc0,
              u16* __restrict__ Wc1, u16* __restrict__ WcO,
              float* __restrict__ barena)
{
    int i = blockIdx.x * 256 + threadIdx.x;
    if (i >= PREP_TOTAL) return;
    if (i >= CVT_TOTAL) {                    // bias arena tail
        int t = i - CVT_TOTAL;
        float v;
        if (t < 2048) {
            int j = t & 511, q = t >> 9;
            v = (q == 0 ? q0b : q == 1 ? k0b : q == 2 ? v0b : s0b)[j];
        } else if (t < 4096) {
            int j = t - 2048; int q = j >> 9; j &= 511;
            v = (q == 0 ? q1b : q == 1 ? k1b : q == 2 ? v1b : s1b)[j];
        } else {
            v = ob[t - 4096];
        }
        barena[t] = v;
        return;
    }
    const float* s; u16* d; int g;
    if (i < XG) { s = x; d = Xb; g = i; }
    else {
        int j = i - XG;
        if (j < 4 * W0G) {
            int q = j / W0G; g = j - q * W0G;
            s = (q == 0 ? q0w : q == 1 ? k0w : q == 2 ? v0w : s0w);
            d = Wc0 + (size_t)q * W0G * 8;
        } else if ((j -= 4 * W0G) < 4 * W1G) {
            int q = j / W1G; g = j - q * W1G;
            s = (q == 0 ? q1w : q == 1 ? k1w : q == 2 ? v1w : s1w);
            d = Wc1 + (size_t)q * W1G * 8;
        } else { j -= 4 * W1G; s = ow; d = WcO; g = j; }
    }
    float4 f0 = ((const float4*)s)[(size_t)g * 2];
    float4 f1 = ((const float4*)s)[(size_t)g * 2 + 1];
    uint4 o;
    o.x = pack2(f0.x, f0.y); o.y = pack2(f0.z, f0.w);
    o.z = pack2(f1.x, f1.y); o.w = pack2(f1.z, f1.w);
    ((uint4*)d)[g] = o;
}

// ---------------------------------------------------------------------------
// CSR build (order within bucket nondeterministic -> only permutes fp adds)
// ---------------------------------------------------------------------------
__global__ __launch_bounds__(256)
void hist_dst(const int* __restrict__ dst, int* __restrict__ deg)
{
    int e = blockIdx.x * 256 + threadIdx.x;
    if (e < NE) atomicAdd(&deg[dst[e]], 1);
}

// single-block scan, 4 elems/thread (13 chunk-iterations)
__global__ __launch_bounds__(1024)
void scan_deg(const int* __restrict__ deg, int* __restrict__ rowptr,
              int* __restrict__ cursor)
{
    __shared__ int wsum[16];
    const int tid = threadIdx.x, lane = tid & 63, wid = tid >> 6;
    int carry = 0;
    for (int base = 0; base < NN; base += 4096) {
        int idx = base + tid * 4;
        int4 v4 = make_int4(0, 0, 0, 0);
        if (idx + 3 < NN)      v4 = *(const int4*)(deg + idx);
        else if (idx < NN) {
            v4.x = deg[idx];
            if (idx + 1 < NN) v4.y = deg[idx + 1];
            if (idx + 2 < NN) v4.z = deg[idx + 2];
        }
        int t0 = v4.x, t1 = t0 + v4.y, t2 = t1 + v4.z, t3 = t2 + v4.w;
        int v = t3;
        #pragma unroll
        for (int off = 1; off < 64; off <<= 1) {
            int t = __shfl_up(v, off, 64);
            if (lane >= off) v += t;
        }
        if (lane == 63) wsum[wid] = v;
        __syncthreads();
        if (wid == 0) {
            int s = (lane < 16) ? wsum[lane] : 0;
            #pragma unroll
            for (int off = 1; off < 16; off <<= 1) {
                int t = __shfl_up(s, off, 16);
                if ((lane & 15) >= off) s += t;
            }
            if (lane < 16) wsum[lane] = s;
        }
        __syncthreads();
        int woff  = (wid == 0) ? 0 : wsum[wid - 1];
        int total = wsum[15];
        int texcl = carry + woff + (v - t3);
        if (idx < NN)     { rowptr[idx]     = texcl;      cursor[idx]     = texcl; }
        if (idx + 1 < NN) { rowptr[idx + 1] = texcl + t0; cursor[idx + 1] = texcl + t0; }
        if (idx + 2 < NN) { rowptr[idx + 2] = texcl + t1; cursor[idx + 2] = texcl + t1; }
        if (idx + 3 < NN) { rowptr[idx + 3] = texcl + t2; cursor[idx + 3] = texcl + t2; }
        carry += total;
        __syncthreads();
    }
    if (tid == 0) rowptr[NN] = NE;
}

__global__ __launch_bounds__(256)
void scatter_edges(const int* __restrict__ src, const int* __restrict__ dst,
                   int* __restrict__ cursor, int* __restrict__ esrc_ord)
{
    int e = blockIdx.x * 256 + threadIdx.x;
    if (e >= NE) return;
    int pos = atomicAdd(&cursor[dst[e]], 1);
    esrc_ord[pos] = src[e];
}

// ---------------------------------------------------------------------------
// Fused per-node attention, 4-edge unrolled + quad prefetch: one wave per dst
// node; online softmax. Four independent shfl-reduce chains per iteration
// overlap their latency. All prefetch branches wave-uniform.
// ---------------------------------------------------------------------------
__global__ __launch_bounds__(256)
void node_attn(const u16* __restrict__ Qb, const u16* __restrict__ Kb,
               const u16* __restrict__ Vb, const int* __restrict__ rowptr,
               const int* __restrict__ esrc, const u16* __restrict__ skipb,
               u16* __restrict__ outb)
{
    int d = blockIdx.x * 4 + (threadIdx.x >> 6);
    if (d >= NN) return;
    int lane = threadIdx.x & 63;

    uint4 qv = *((const uint4*)(Qb + (size_t)d * HC) + lane);
    float q[8] = { bflo(qv.x), bfhi(qv.x), bflo(qv.y), bfhi(qv.y),
                   bflo(qv.z), bfhi(qv.z), bflo(qv.w), bfhi(qv.w) };

    int beg = rowptr[d], end = rowptr[d + 1];
    int n = end - beg;
    float m = -INFINITY, den = 0.f;
    float acc[8] = {};

    uint4 k0, k1, k2, k3, v0, v1, v2, v3;
    if (n > 0){ int s = esrc[beg];     k0 = *((const uint4*)(Kb + (size_t)s * HC) + lane);
                                       v0 = *((const uint4*)(Vb + (size_t)s * HC) + lane); }
    if (n > 1){ int s = esrc[beg + 1]; k1 = *((const uint4*)(Kb + (size_t)s * HC) + lane);
                                       v1 = *((const uint4*)(Vb + (size_t)s * HC) + lane); }
    if (n > 2){ int s = esrc[beg + 2]; k2 = *((const uint4*)(Kb + (size_t)s * HC) + lane);
                                       v2 = *((const uint4*)(Vb + (size_t)s * HC) + lane); }
    if (n > 3){ int s = esrc[beg + 3]; k3 = *((const uint4*)(Kb + (size_t)s * HC) + lane);
                                       v3 = *((const uint4*)(Vb + (size_t)s * HC) + lane); }

    auto single = [&](uint4 kk, uint4 vv){
        float s0 = dot8(q, kk);
        #pragma unroll
        for (int off = 1; off < 16; off <<= 1) s0 += __shfl_xor(s0, off, 64);
        float a0 = s0 * 0.08838834764831845f;
        float mnew = fmaxf(m, a0);
        float sc = __expf(m - mnew);
        float p0 = __expf(a0 - mnew);
        den = den * sc + p0;
        acc[0] = acc[0] * sc + p0 * bflo(vv.x);
        acc[1] = acc[1] * sc + p0 * bfhi(vv.x);
        acc[2] = acc[2] * sc + p0 * bflo(vv.y);
        acc[3] = acc[3] * sc + p0 * bfhi(vv.y);
        acc[4] = acc[4] * sc + p0 * bflo(vv.z);
        acc[5] = acc[5] * sc + p0 * bfhi(vv.z);
        acc[6] = acc[6] * sc + p0 * bflo(vv.w);
        acc[7] = acc[7] * sc + p0 * bfhi(vv.w);
        m = mnew;
    };

    int i = beg;
    for (; i + 3 < end; i += 4) {
        float s0 = dot8(q, k0), s1 = dot8(q, k1), s2 = dot8(q, k2), s3 = dot8(q, k3);
        bool h0 = i + 4 < end, h1 = i + 5 < end, h2 = i + 6 < end, h3 = i + 7 < end;
        int sn0 = 0, sn1 = 0, sn2 = 0, sn3 = 0;
        if (h0) sn0 = esrc[i + 4];
        if (h1) sn1 = esrc[i + 5];
        if (h2) sn2 = esrc[i + 6];
        if (h3) sn3 = esrc[i + 7];
        if (h0) k0 = *((const uint4*)(Kb + (size_t)sn0 * HC) + lane);   // k consumed
        if (h1) k1 = *((const uint4*)(Kb + (size_t)sn1 * HC) + lane);
        if (h2) k2 = *((const uint4*)(Kb + (size_t)sn2 * HC) + lane);
        if (h3) k3 = *((const uint4*)(Kb + (size_t)sn3 * HC) + lane);
        #pragma unroll
        for (int off = 1; off < 16; off <<= 1) {   // four chains interleave
            s0 += __shfl_xor(s0, off, 64);
            s1 += __shfl_xor(s1, off, 64);
            s2 += __shfl_xor(s2, off, 64);
            s3 += __shfl_xor(s3, off, 64);
        }
        float a0 = s0 * 0.08838834764831845f;
        float a1 = s1 * 0.08838834764831845f;
        float a2 = s2 * 0.08838834764831845f;
        float a3 = s3 * 0.08838834764831845f;

        float mnew = fmaxf(fmaxf(fmaxf(a0, a1), fmaxf(a2, a3)), m);
        float sc = __expf(m - mnew);
        float p0 = __expf(a0 - mnew), p1 = __expf(a1 - mnew);
        float p2 = __expf(a2 - mnew), p3 = __expf(a3 - mnew);
        den = den * sc + ((p0 + p1) + (p2 + p3));

        acc[0] = acc[0] * sc + p0 * bflo(v0.x) + p1 * bflo(v1.x) + p2 * bflo(v2.x) + p3 * bflo(v3.x);
        acc[1] = acc[1] * sc + p0 * bfhi(v0.x) + p1 * bfhi(v1.x) + p2 * bfhi(v2.x) + p3 * bfhi(v3.x);
        acc[2] = acc[2] * sc + p0 * bflo(v0.y) + p1 * bflo(v1.y) + p2 * bflo(v2.y) + p3 * bflo(v3.y);
        acc[3] = acc[3] * sc + p0 * bfhi(v0.y) + p1 * bfhi(v1.y) + p2 * bfhi(v2.y) + p3 * bfhi(v3.y);
        acc[4] = acc[4] * sc + p0 * bflo(v0.z) + p1 * bflo(v1.z) + p2 * bflo(v2.z) + p3 * bflo(v3.z);
        acc[5] = acc[5] * sc + p0 * bfhi(v0.z) + p1 * bfhi(v1.z) + p2 * bfhi(v2.z) + p3 * bfhi(v3.z);
        acc[6] = acc[6] * sc + p0 * bflo(v0.w) + p1 * bflo(v1.w) + p2 * bflo(v2.w) + p3 * bflo(v3.w);
        acc[7] = acc[7] * sc + p0 * bfhi(v0.w) + p1 * bfhi(v1.w) + p2 * bfhi(v2.w) + p3 * bfhi(v3.w);
        m = mnew;

        if (h0) v0 = *((const uint4*)(Vb + (size_t)sn0 * HC) + lane);   // v consumed
        if (h1) v1 = *((const uint4*)(Vb + (size_t)sn1 * HC) + lane);
        if (h2) v2 = *((const uint4*)(Vb + (size_t)sn2 * HC) + lane);
        if (h3) v3 = *((const uint4*)(Vb + (size_t)sn3 * HC) + lane);
    }
    if (i < end)     single(k0, v0);    // tail: regs hold edges i, i+1, i+2
    if (i + 1 < end) single(k1, v1);
    if (i + 2 < end) single(k2, v2);

    float inv = 1.f / (den + 1e-16f);
    size_t base = (size_t)d * HC + lane * 8;
    uint4 sv = *((const uint4*)(skipb + base));
    float sk[8] = { bflo(sv.x), bfhi(sv.x), bflo(sv.y), bfhi(sv.y),
                    bflo(sv.z), bfhi(sv.z), bflo(sv.w), bfhi(sv.w) };
    uint4 o;
    o.x = pack2(fmaxf(acc[0] * inv + sk[0], 0.f), fmaxf(acc[1] * inv + sk[1], 0.f));
    o.y = pack2(fmaxf(acc[2] * inv + sk[2], 0.f), fmaxf(acc[3] * inv + sk[3], 0.f));
    o.z = pack2(fmaxf(acc[4] * inv + sk[4], 0.f), fmaxf(acc[5] * inv + sk[5], 0.f));
    o.w = pack2(fmaxf(acc[6] * inv + sk[6], 0.f), fmaxf(acc[7] * inv + sk[7], 0.f));
    *(uint4*)(outb + base) = o;
}

// ---------------------------------------------------------------------------
extern "C" void kernel_launch(void* const* d_in, const int* in_sizes, int n_in,
                              void* d_out, int out_size, void* d_ws, size_t ws_size,
                              hipStream_t stream)
{
    const float* x   = (const float*)d_in[0];
    const int* ei    = (const int*)d_in[1];
    const int* esrc  = ei;
    const int* edst  = ei + NE;
    const float* q0w = (const float*)d_in[2];  const float* q0b = (const float*)d_in[3];
    const float* k0w = (const float*)d_in[4];  const float* k0b = (const float*)d_in[5];
    const float* v0w = (const float*)d_in[6];  const float* v0b = (const float*)d_in[7];
    const float* s0w = (const float*)d_in[8];  const float* s0b = (const float*)d_in[9];
    const float* q1w = (const float*)d_in[10]; const float* q1b = (const float*)d_in[11];
    const float* k1w = (const float*)d_in[12]; const float* k1b = (const float*)d_in[13];
    const float* v1w = (const float*)d_in[14]; const float* v1b = (const float*)d_in[15];
    const float* s1w = (const float*)d_in[16]; const float* s1b = (const float*)d_in[17];
    const float* ow  = (const float*)d_in[18]; const float* obs = (const float*)d_in[19];

    // ---- workspace (~247 MB) ----
    char* p = (char*)d_ws;
    auto take = [&](size_t bytes) { void* r = (void*)p; p += (bytes + 255) & ~(size_t)255; return r; };
    u16*   Qb     = (u16*)take((size_t)NN * HC * 2);       // 51.2 MB
    u16*   Vb     = (u16*)take((size_t)NN * HC * 2);       // 51.2 MB
    u16*   Hb     = (u16*)take((size_t)NN * HC * 2);       // 51.2 MB
    u16*   Sb     = (u16*)take((size_t)NN * HC * 2);       // 51.2 MB (bf16 skip)
    u16*   Xb     = (u16*)take((size_t)NN * DD * 2);       // 38.4 MB (bf16 x)
    u16*   Wc0    = (u16*)take((size_t)2048 * DD * 2);     // 1.57 MB
    u16*   Wc1    = (u16*)take((size_t)2048 * HC * 2);     // 2.10 MB
    u16*   WcO    = (u16*)take((size_t)DD * HC * 2);       // 0.39 MB
    float* barena = (float*)take(4480 * 4);                // 17.9 KB

    // ---- scratch carved from d_out (dead before final GEMM overwrites all) ----
    char* dob = (char*)d_out;
    u16* Kb       = (u16*)dob;                             // 51.2 MB
    int* deg      = (int*)(dob + 51200000);
    int* rowptr   = (int*)(dob + 51400192);                // NN+1
    int* cursor   = (int*)(dob + 51600384);
    int* esrc_ord = (int*)(dob + 51800576);                // 1.6 MB

    dim3 blk(256);
    int gE   = (NE + 255) / 256;
    int gnod = (NN + 3) / 4;

    // ---- prep (1 launch) + CSR build ----
    prep_all<<<(PREP_TOTAL + 255) / 256, blk, 0, stream>>>(x,
        q0w, k0w, v0w, s0w, q1w, k1w, v1w, s1w, ow,
        q0b, k0b, v0b, s0b, q1b, k1b, v1b, s1b, obs,
        Xb, Wc0, Wc1, WcO, barena);
    hipMemsetAsync(deg, 0, (size_t)NN * 4, stream);
    hist_dst      <<<gE, blk, 0, stream>>>(edst, deg);
    scan_deg      <<<1, 1024, 0, stream>>>(deg, rowptr, cursor);
    scatter_edges <<<gE, blk, 0, stream>>>(esrc, edst, cursor, esrc_ord);

    // ---- layer 0 (A = Xb bf16, K=384) ----
    gemm_ws<DD><<<256, 512, 0, stream>>>(Xb, Wc0, barena, Qb, Kb, Vb, Sb);
    node_attn<<<gnod, blk, 0, stream>>>(Qb, Kb, Vb, rowptr, esrc_ord, Sb, Hb);

    // ---- layer 1 (A = Hb bf16, K=512) ----
    gemm_ws<HC><<<256, 512, 0, stream>>>(Hb, Wc1, barena + 2048, Qb, Kb, Vb, Sb);
    node_attn<<<gnod, blk, 0, stream>>>(Qb, Kb, Vb, rowptr, esrc_ord, Sb, Hb);

    // ---- output projection (weight-stationary, fp32, overwrites ALL of d_out) ----
    gemm_ws_f<<<240, 512, 0, stream>>>(Hb, WcO, barena + 4096, (float*)d_out);
}